// Round 1
// 979.303 us; speedup vs baseline: 1.0434x; 1.0434x over previous
//
#include <hip/hip_runtime.h>
#include <cmath>

typedef __bf16 bf16;
typedef __bf16 bf16x2 __attribute__((ext_vector_type(2)));
typedef __bf16 bf16x4 __attribute__((ext_vector_type(4)));
typedef __bf16 bf16x8 __attribute__((ext_vector_type(8)));
typedef float  f32x4  __attribute__((ext_vector_type(4)));

#define AS1(p) ((const __attribute__((address_space(1))) void*)(p))
#define AS3(p) ((__attribute__((address_space(3))) void*)(p))

// problem constants
constexpr int Bc = 2, Tc = 4096, Dc = 1024, Hc = 16, Fc = 4096, Kc = 2048;

// ---------------------------------------------------------------- init (defensive: no poison survives)
__global__ __launch_bounds__(256) void init_kernel(int* __restrict__ slot,
    int* __restrict__ sel, float* __restrict__ gate){
  int i = blockIdx.x * 256 + threadIdx.x;          // grid 32 -> 8192
  slot[i] = -1;
  if (i < Bc * Kc){ sel[i] = i & (Kc - 1); gate[i] = 0.f; }
}

// ---------------------------------------------------------------- router (fp32)
__global__ __launch_bounds__(256) void router_kernel(const float* __restrict__ x,
    const float* __restrict__ rw, const float* __restrict__ rb, float* __restrict__ logits){
  int wv = threadIdx.x >> 6, lane = threadIdx.x & 63;
  int token = blockIdx.x * 4 + wv;                 // grid 2048 -> 8192 tokens
  const float* xr = x + (size_t)token * Dc;
  float s = 0.f;
#pragma unroll
  for (int i = 0; i < 16; i++){ int d = lane + i*64; s += xr[d] * rw[d]; }
#pragma unroll
  for (int m = 32; m; m >>= 1) s += __shfl_xor(s, m);
  if (lane == 0) logits[token] = s + rb[0];
}

// ---------------------------------------------------------------- top-k by rank counting
__global__ __launch_bounds__(256) void topk_kernel(const float* __restrict__ logits,
    int* __restrict__ slot, int* __restrict__ sel, float* __restrict__ gate){
  __shared__ float lg[Tc];
  int b = blockIdx.x >> 4, seg = blockIdx.x & 15;  // grid 32
  const float* lb = logits + (size_t)b * Tc;
  for (int i = threadIdx.x; i < Tc; i += 256) lg[i] = lb[i];
  __syncthreads();
  int t = seg * 256 + threadIdx.x;
  float v = lg[t];
  int rank = 0;
  for (int j = 0; j < Tc; j++){
    float u = lg[j];
    rank += (u > v) || (u == v && j < t);          // strict total order == JAX top_k
  }
  if (rank < Kc){
    sel [b*Kc + rank] = t;
    gate[b*Kc + rank] = 1.f / (1.f + expf(-v));
    slot[b*Tc + t] = rank;
  }
}

// ---------------------------------------------------------------- gather to fp32 h
__global__ __launch_bounds__(256) void gather_kernel(const float* __restrict__ x,
    const int* __restrict__ sel, float* __restrict__ h){
  int row = blockIdx.x;                            // b*Kc + k, grid 4096
  int b = row >> 11;
  int t = sel[row];
  t = (t < 0) ? 0 : (t >= Tc ? Tc - 1 : t);        // clamp: fault -> wrong answer
  const float* xr = x + ((size_t)b * Tc + t) * Dc;
  float* hr = h + (size_t)row * Dc;
  int d = threadIdx.x * 4;
  *(float4*)(hr + d) = *(const float4*)(xr + d);
}

// ---------------------------------------------------------------- layernorm fp32->bf16
__global__ __launch_bounds__(256) void ln_kernel(const float* __restrict__ h,
    const float* __restrict__ w, const float* __restrict__ bb, bf16* __restrict__ y){
  __shared__ float red[4], red2[4];
  int row = blockIdx.x, t = threadIdx.x;
  int wv = t >> 6, lane = t & 63;
  const float* hr = h + (size_t)row * Dc;
  float4 x4 = *(const float4*)(hr + t*4);
  float s = x4.x + x4.y + x4.z + x4.w;
#pragma unroll
  for (int m = 32; m; m >>= 1) s += __shfl_xor(s, m);
  if (lane == 0) red[wv] = s;
  __syncthreads();
  float mu = (red[0]+red[1]+red[2]+red[3]) * (1.f/Dc);
  float d0 = x4.x-mu, d1 = x4.y-mu, d2 = x4.z-mu, d3 = x4.w-mu;
  float q = d0*d0 + d1*d1 + d2*d2 + d3*d3;
#pragma unroll
  for (int m = 32; m; m >>= 1) q += __shfl_xor(q, m);
  if (lane == 0) red2[wv] = q;
  __syncthreads();
  float var = (red2[0]+red2[1]+red2[2]+red2[3]) * (1.f/Dc);
  float rs = rsqrtf(var + 1e-5f);
  bf16* yr = y + (size_t)row * Dc;
  int d = t * 4;
  float xv[4] = {x4.x, x4.y, x4.z, x4.w};
#pragma unroll
  for (int i = 0; i < 4; i++)
    yr[d+i] = (bf16)((xv[i]-mu) * rs * w[d+i] + bb[d+i]);
}

// ---------------------------------------------------------------- weight transpose fp32 -> bf16
__global__ __launch_bounds__(256) void transpose_kernel(const float* __restrict__ in,
    bf16* __restrict__ out, int R, int C){
  __shared__ __attribute__((aligned(16))) bf16 tile[64][72];
  int c0 = blockIdx.x * 64, r0 = blockIdx.y * 64;
  int t = threadIdx.x;
#pragma unroll
  for (int i = 0; i < 2; i++){
    int ch = t + i*256;
    int row = ch >> 3, col8 = (ch & 7) * 8;
    const float* src = in + (size_t)(r0+row)*C + c0 + col8;
    float4 a = *(const float4*)src;
    float4 b = *(const float4*)(src + 4);
    bf16x8 v;
    v[0]=(bf16)a.x; v[1]=(bf16)a.y; v[2]=(bf16)a.z; v[3]=(bf16)a.w;
    v[4]=(bf16)b.x; v[5]=(bf16)b.y; v[6]=(bf16)b.z; v[7]=(bf16)b.w;
    *(bf16x8*)&tile[row][col8] = v;
  }
  __syncthreads();
#pragma unroll
  for (int i = 0; i < 2; i++){
    int ch = t + i*256;
    int orow = ch >> 3, oc8 = (ch & 7) * 8;
    bf16x8 v;
#pragma unroll
    for (int j = 0; j < 8; j++) v[j] = tile[oc8+j][orow];
    *(bf16x8*)(out + (size_t)(c0+orow)*R + r0 + oc8) = v;
  }
}

// fast gelu (tanh approx == sigmoid form), exp2-based
__device__ __forceinline__ float fast_gelu(float v){
  float u = exp2f(v * (1.f + 0.044715f*v*v) * -2.30220772f);  // 2*0.79788456*log2(e)
  return v * __builtin_amdgcn_rcpf(1.f + u);
}

// ---------------------------------------------------------------- MFMA GEMM 128x128: C = A[M,Kd] * Bt[N,Kd]^T
// mode 0: Cbf = bf16(acc); mode 1: Cf += acc (fp32 residual); mode 2: Cbf = bf16(gelu(acc))
__global__ __launch_bounds__(256) void gemm_bt_kernel(
    const bf16* __restrict__ A, const bf16* __restrict__ Bt,
    bf16* __restrict__ Cbf, float* __restrict__ Cf,
    int M, int N, int Kd, int mode)
{
  __shared__ __attribute__((aligned(16))) bf16 As[128*32];
  __shared__ __attribute__((aligned(16))) bf16 Bs[128*32];
  const int tid = threadIdx.x;
  const int wv = tid >> 6, lane = tid & 63;
  const int wm = wv & 1, wn = wv >> 1;
  const int m0 = blockIdx.y * 128, n0 = blockIdx.x * 128;
  f32x4 acc[4][4] = {};

  const bf16* Ag  = A  + (size_t)(m0      + (tid>>2)) * Kd + (tid&3)*8;
  const bf16* Ag2 = A  + (size_t)(m0 + 64 + (tid>>2)) * Kd + (tid&3)*8;
  const bf16* Bg  = Bt + (size_t)(n0      + (tid>>2)) * Kd + (tid&3)*8;
  const bf16* Bg2 = Bt + (size_t)(n0 + 64 + (tid>>2)) * Kd + (tid&3)*8;
  char* AsB = (char*)As;
  char* BsB = (char*)Bs;

  for (int k0 = 0; k0 < Kd; k0 += 32){
    __syncthreads();
    __builtin_amdgcn_global_load_lds(AS1(Ag  + k0), AS3(AsB +        wv*1024), 16, 0, 0);
    __builtin_amdgcn_global_load_lds(AS1(Ag2 + k0), AS3(AsB + 4096 + wv*1024), 16, 0, 0);
    __builtin_amdgcn_global_load_lds(AS1(Bg  + k0), AS3(BsB +        wv*1024), 16, 0, 0);
    __builtin_amdgcn_global_load_lds(AS1(Bg2 + k0), AS3(BsB + 4096 + wv*1024), 16, 0, 0);
    __syncthreads();
    bf16x8 af[4], bfr[4];
    const bf16* Ab = As + (wm*64 + (lane&15))*32 + (lane>>4)*8;
    const bf16* Bb = Bs + (wn*64 + (lane&15))*32 + (lane>>4)*8;
#pragma unroll
    for (int mt = 0; mt < 4; mt++) af[mt]  = *(const bf16x8*)(Ab + mt*16*32);
#pragma unroll
    for (int nt = 0; nt < 4; nt++) bfr[nt] = *(const bf16x8*)(Bb + nt*16*32);
#pragma unroll
    for (int mt = 0; mt < 4; mt++)
#pragma unroll
      for (int nt = 0; nt < 4; nt++)
        acc[mt][nt] = __builtin_amdgcn_mfma_f32_16x16x32_bf16(af[mt], bfr[nt], acc[mt][nt], 0, 0, 0);
  }
#pragma unroll
  for (int mt = 0; mt < 4; mt++){
    int rr0 = m0 + wm*64 + mt*16 + (lane>>4)*4;
#pragma unroll
    for (int nt = 0; nt < 4; nt++){
      int cc = n0 + wn*64 + nt*16 + (lane&15);
#pragma unroll
      for (int r = 0; r < 4; r++){
        float v = acc[mt][nt][r];
        size_t idx = (size_t)(rr0 + r) * N + cc;
        if (mode == 0)      Cbf[idx] = (bf16)v;
        else if (mode == 1) Cf[idx] += v;
        else                Cbf[idx] = (bf16)fast_gelu(v);
      }
    }
  }
}

// ---------------------------------------------------------------- MFMA GEMM 128x64 (for N=1024: 2 blocks/CU)
__global__ __launch_bounds__(256) void gemm_bt64_kernel(
    const bf16* __restrict__ A, const bf16* __restrict__ Bt,
    bf16* __restrict__ Cbf, float* __restrict__ Cf,
    int M, int N, int Kd, int mode)
{
  __shared__ __attribute__((aligned(16))) bf16 As[128*32];
  __shared__ __attribute__((aligned(16))) bf16 Bs[64*32];
  const int tid = threadIdx.x;
  const int wv = tid >> 6, lane = tid & 63;
  const int wm = wv >> 1, wn = wv & 1;            // 2x2 waves: wave = 64(m) x 32(n)
  const int m0 = blockIdx.y * 128, n0 = blockIdx.x * 64;
  f32x4 acc[4][2] = {};

  const bf16* Ag  = A  + (size_t)(m0      + (tid>>2)) * Kd + (tid&3)*8;
  const bf16* Ag2 = A  + (size_t)(m0 + 64 + (tid>>2)) * Kd + (tid&3)*8;
  const bf16* Bg  = Bt + (size_t)(n0      + (tid>>2)) * Kd + (tid&3)*8;
  char* AsB = (char*)As;
  char* BsB = (char*)Bs;

  for (int k0 = 0; k0 < Kd; k0 += 32){
    __syncthreads();
    __builtin_amdgcn_global_load_lds(AS1(Ag  + k0), AS3(AsB +        wv*1024), 16, 0, 0);
    __builtin_amdgcn_global_load_lds(AS1(Ag2 + k0), AS3(AsB + 4096 + wv*1024), 16, 0, 0);
    __builtin_amdgcn_global_load_lds(AS1(Bg  + k0), AS3(BsB +        wv*1024), 16, 0, 0);
    __syncthreads();
    bf16x8 af[4], bfr[2];
    const bf16* Ab = As + (wm*64 + (lane&15))*32 + (lane>>4)*8;
    const bf16* Bb = Bs + (wn*32 + (lane&15))*32 + (lane>>4)*8;
#pragma unroll
    for (int mt = 0; mt < 4; mt++) af[mt]  = *(const bf16x8*)(Ab + mt*16*32);
#pragma unroll
    for (int nt = 0; nt < 2; nt++) bfr[nt] = *(const bf16x8*)(Bb + nt*16*32);
#pragma unroll
    for (int mt = 0; mt < 4; mt++)
#pragma unroll
      for (int nt = 0; nt < 2; nt++)
        acc[mt][nt] = __builtin_amdgcn_mfma_f32_16x16x32_bf16(af[mt], bfr[nt], acc[mt][nt], 0, 0, 0);
  }
#pragma unroll
  for (int mt = 0; mt < 4; mt++){
    int rr0 = m0 + wm*64 + mt*16 + (lane>>4)*4;
#pragma unroll
    for (int nt = 0; nt < 2; nt++){
      int cc = n0 + wn*32 + nt*16 + (lane&15);
#pragma unroll
      for (int r = 0; r < 4; r++){
        float v = acc[mt][nt][r];
        size_t idx = (size_t)(rr0 + r) * N + cc;
        if (mode == 0)      Cbf[idx] = (bf16)v;
        else if (mode == 1) Cf[idx] += v;
        else                Cbf[idx] = (bf16)fast_gelu(v);
      }
    }
  }
}

// ---------------------------------------------------------------- flash attention v4
// grid 1024 = 32 qtiles x 16 heads x 2 batch; 256 threads; wave owns 16 q-rows.
// v4 changes vs v3 (VALU/LDS-issue-bound per rocprof: VALUBusy 59%, MfmaUtil 12%):
//  - defer-max (T13, THR=8): skip 16-lane max reduce + alpha rescale when
//    __all(local tile max <= mrow + 8); P bounded by 2^8, O = oacc/l exact.
//  - transposed-P LDS (Pt[k][q]): 4x ds_write_b64 packed stores +
//    4x ds_read_b64_tr_b16 HW-transpose reads replace 16x ds_write_b16 +
//    2x ds_read_b128 (kills the b16-store bank conflicts too).
//  - s_setprio(1) around MFMA clusters (T5, attn-positive per m191).
__global__ __launch_bounds__(256) void flash_kernel(const bf16* __restrict__ qkv, bf16* __restrict__ o){
  __shared__ __attribute__((aligned(16))) bf16 Ks[64][72];
  __shared__ __attribute__((aligned(16))) bf16 Vt[64*64];
  __shared__ __attribute__((aligned(16))) bf16 Pt[4][64][16];  // per-wave P, transposed [kcol][qrow]
  const int tid = threadIdx.x, wv = tid >> 6, lane = tid & 63;
  const int quad = lane >> 4, l15 = lane & 15;
  const int bid = blockIdx.x;
  const int qt = bid & 31, hh = (bid >> 5) & 15, b = bid >> 9;
  const int q0 = qt * 64;
  const size_t base = (size_t)b * Kc * (3*Dc);
  const float SC2 = 0.125f * 1.44269504f;          // 1/sqrt(64) * log2(e)

  const int sp8 = (tid & 7) * 8;                   // d-col group for staging
  const int kr0 = tid >> 3, kr1 = kr0 + 32;        // K staging rows
  const int vr0 = (tid >> 3) * 2;                  // V staging rows (pair vr0, vr0+1)
  const int vg = vr0 >> 3, vlo = vr0 & 7, vsw = sp8 >> 3;

  // Q direct to registers (A-frag)
  bf16x8 qf[2];
  {
    const bf16* qr = qkv + base + (size_t)(q0 + wv*16 + l15)*(3*Dc) + hh*64 + quad*8;
    qf[0] = *(const bf16x8*)(qr);
    qf[1] = *(const bf16x8*)(qr + 32);
  }

  // prefetch K/V tile 0
  const bf16* kp0 = qkv + base + (size_t)kr0*(3*Dc) +   Dc + hh*64 + sp8;
  const bf16* kp1 = qkv + base + (size_t)kr1*(3*Dc) +   Dc + hh*64 + sp8;
  const bf16* vp0 = qkv + base + (size_t)vr0*(3*Dc) + 2*Dc + hh*64 + sp8;
  const bf16* vp1 = vp0 + 3*Dc;
  bf16x8 kpre0 = *(const bf16x8*)kp0;
  bf16x8 kpre1 = *(const bf16x8*)kp1;
  bf16x8 vpre0 = *(const bf16x8*)vp0;
  bf16x8 vpre1 = *(const bf16x8*)vp1;
  const int TSTRIDE = 64 * 3 * Dc;

  // ones B-frag: column 0 of the virtual 5th V tile
  bf16x8 onesf;
#pragma unroll
  for (int j = 0; j < 8; j++) onesf[j] = (bf16)(l15 == 0 ? 1.f : 0.f);

  f32x4 oacc[4] = {};
  f32x4 oacc5 = {};                                 // row-sums of P (alpha-chained)
  float mrow[4];
#pragma unroll
  for (int r = 0; r < 4; r++) mrow[r] = -1e30f;

  for (int kt = 0; kt < 32; kt++){
    __syncthreads();                               // prev tile's readers done
    // stage K (b128) and V (packed kv-pairs, b32)
    *(bf16x8*)&Ks[kr0][sp8] = kpre0;
    *(bf16x8*)&Ks[kr1][sp8] = kpre1;
#pragma unroll
    for (int j = 0; j < 8; j++){
      bf16x2 pr; pr[0] = vpre0[j]; pr[1] = vpre1[j];
      *(bf16x2*)&Vt[(sp8 + j)*64 + ((vg ^ j ^ vsw) << 3) + vlo] = pr;
    }
    __syncthreads();
    // prefetch next tile (overlaps compute below)
    if (kt < 31){
      kp0 += TSTRIDE; kp1 += TSTRIDE; vp0 += TSTRIDE; vp1 += TSTRIDE;
      kpre0 = *(const bf16x8*)kp0;
      kpre1 = *(const bf16x8*)kp1;
      vpre0 = *(const bf16x8*)vp0;
      vpre1 = *(const bf16x8*)vp1;
    }
    // S = Q K^T
    f32x4 sacc[4] = {};
    __builtin_amdgcn_s_setprio(1);
#pragma unroll
    for (int nt = 0; nt < 4; nt++)
#pragma unroll
      for (int s = 0; s < 2; s++){
        bf16x8 kf = *(const bf16x8*)&Ks[nt*16 + l15][s*32 + quad*8];
        sacc[nt] = __builtin_amdgcn_mfma_f32_16x16x32_bf16(qf[s], kf, sacc[nt], 0, 0, 0);
      }
    __builtin_amdgcn_s_setprio(0);
    // ---- online softmax, exp2 domain, deferred rescale (THR = 8) ----
    // row = quad*4 + r; the 16 l15-lanes of a quad share a row (and its mrow).
    float lm[4];
#pragma unroll
    for (int r = 0; r < 4; r++)
      lm[r] = fmaxf(fmaxf(sacc[0][r], sacc[1][r]), fmaxf(sacc[2][r], sacc[3][r]));
    bool ok = true;
#pragma unroll
    for (int r = 0; r < 4; r++) ok = ok && (lm[r] * SC2 <= mrow[r] + 8.f);
    if (!__all((int)ok)){
      // slow path: full 16-lane max reduce + alpha rescale (tile 0 + rare growth)
#pragma unroll
      for (int r = 0; r < 4; r++){
        float mx = lm[r];
#pragma unroll
        for (int m = 1; m < 16; m <<= 1) mx = fmaxf(mx, __shfl_xor(mx, m));
        float nm = fmaxf(mrow[r], mx * SC2);
        float alpha = exp2f(mrow[r] - nm);
        mrow[r] = nm;
#pragma unroll
        for (int nt = 0; nt < 4; nt++) oacc[nt][r] *= alpha;
        oacc5[r] *= alpha;
      }
    }
    // P = exp2(S*SC2 - mrow) (bounded by 2^8 under deferral), stored transposed:
    // Pt[wv][k = nt*16+l15][q = quad*4+r] -- one packed b64 store per nt
#pragma unroll
    for (int nt = 0; nt < 4; nt++){
      bf16x4 w;
#pragma unroll
      for (int r = 0; r < 4; r++) w[r] = (bf16)exp2f(fmaf(sacc[nt][r], SC2, -mrow[r]));
      *(bf16x4*)&Pt[wv][nt*16 + l15][quad*4] = w;
    }
    // A-frag via HW transpose read: pf[s][j] = Pt[wv][s*32+quad*8+j][l15].
    // tr_b16: lane reads 4 bf16 at its elem addr + {0,16,32,48} elems.
    bf16x8 pf[2];
    {
      bf16x4 t00, t01, t10, t11;
      const bf16* pr0 = &Pt[wv][     quad*8][l15];
      const bf16* pr1 = &Pt[wv][32 + quad*8][l15];
      asm volatile("ds_read_b64_tr_b16 %0, %1"            : "=v"(t00) : "v"(AS3(pr0)) : "memory");
      asm volatile("ds_read_b64_tr_b16 %0, %1 offset:128" : "=v"(t01) : "v"(AS3(pr0)) : "memory");
      asm volatile("ds_read_b64_tr_b16 %0, %1"            : "=v"(t10) : "v"(AS3(pr1)) : "memory");
      asm volatile("ds_read_b64_tr_b16 %0, %1 offset:128" : "=v"(t11) : "v"(AS3(pr1)) : "memory");
      asm volatile("s_waitcnt lgkmcnt(0)" ::: "memory");   // rule #18 fence
      __builtin_amdgcn_sched_barrier(0);
#pragma unroll
      for (int j = 0; j < 4; j++){
        pf[0][j] = t00[j]; pf[0][j+4] = t01[j];
        pf[1][j] = t10[j]; pf[1][j+4] = t11[j];
      }
    }
    // PV with swizzled Vt reads + ones-column row-sum
    __builtin_amdgcn_s_setprio(1);
#pragma unroll
    for (int nt = 0; nt < 4; nt++){
      int d = nt*16 + l15;
      int sw = (d & 7) ^ ((d >> 3) & 7);
#pragma unroll
      for (int s = 0; s < 2; s++){
        bf16x8 vf = *(const bf16x8*)&Vt[d*64 + (((s*4 + quad) ^ sw) << 3)];
        oacc[nt] = __builtin_amdgcn_mfma_f32_16x16x32_bf16(pf[s], vf, oacc[nt], 0, 0, 0);
      }
    }
    oacc5 = __builtin_amdgcn_mfma_f32_16x16x32_bf16(pf[0], onesf, oacc5, 0, 0, 0);
    oacc5 = __builtin_amdgcn_mfma_f32_16x16x32_bf16(pf[1], onesf, oacc5, 0, 0, 0);
    __builtin_amdgcn_s_setprio(0);
  }
  // epilogue: l lives in lane (quad*16 + 0) of each quad-group, col 0
#pragma unroll
  for (int r = 0; r < 4; r++){
    float l = __shfl(oacc5[r], lane & 48);
    float inv = __builtin_amdgcn_rcpf(l);
    int row = q0 + wv*16 + quad*4 + r;
#pragma unroll
    for (int nt = 0; nt < 4; nt++)
      o[((size_t)b*Kc + row)*Dc + hh*64 + nt*16 + l15] = (bf16)(oacc[nt][r] * inv);
  }
}

// ---------------------------------------------------------------- scatter-add to fp32 output
__global__ __launch_bounds__(256) void scatter_kernel(const float* __restrict__ x,
    const float* __restrict__ h, const float* __restrict__ gate,
    const int* __restrict__ slot, float* __restrict__ out){
  int row = blockIdx.x;                       // b*Tc + t, grid 8192
  int b = row >> 12;
  int d = threadIdx.x * 4;
  const float* xr = x + (size_t)row * Dc;
  float* orow = out + (size_t)row * Dc;
  int sl = slot[row];
  if (sl >= 0 && sl < Kc){
    float g = gate[b*Kc + sl];
    const float* hr = h + ((size_t)b*Kc + sl) * Dc;
    float4 xv = *(const float4*)(xr + d);
    float4 hv = *(const float4*)(hr + d);
    float4 ov = { xv.x + g*hv.x, xv.y + g*hv.y, xv.z + g*hv.z, xv.w + g*hv.w };
    *(float4*)(orow + d) = ov;
  } else {
    *(float4*)(orow + d) = *(const float4*)(xr + d);
  }
}

// ---------------------------------------------------------------- launch
extern "C" void kernel_launch(void* const* d_in, const int* in_sizes, int n_in,
                              void* d_out, int out_size, void* d_ws, size_t ws_size,
                              hipStream_t stream)
{
  const float* x        = (const float*)d_in[0];
  const float* router_w = (const float*)d_in[1];
  const float* router_b = (const float*)d_in[2];
  const float* ln1_w    = (const float*)d_in[3];
  const float* ln1_b    = (const float*)d_in[4];
  const float* wqkv     = (const float*)d_in[5];
  const float* wo       = (const float*)d_in[6];
  const float* ln2_w    = (const float*)d_in[7];
  const float* ln2_b    = (const float*)d_in[8];
  const float* w1       = (const float*)d_in[9];
  const float* w2       = (const float*)d_in[10];
  float* out = (float*)d_out;

  // workspace layout (bytes), 4 KB pad between regions
  char* ws = (char*)d_ws;
  if (ws_size < 84029440u) return;
  float* logits = (float*)(ws + 0);            //  32768
  int*   slot   = (int*)  (ws + 36864);        //  32768
  int*   sel    = (int*)  (ws + 73728);        //  16384
  float* gate   = (float*)(ws + 94208);        //  16384
  float* h      = (float*)(ws + 114688);       //  16 MB fp32 residual stream [4096,1024]
  bf16*  y      = (bf16*) (ws + 16896000);     //  8 MB  (aliases attention output o)
  bf16*  big    = (bf16*) (ws + 25288704);     //  32 MB (qkv [4096,3072] / gelu [4096,4096])
  bf16*  wqkvT  = (bf16*) (ws + 58847232);     //  6 MB
  bf16*  woT    = (bf16*) (ws + 65142784);     //  2 MB
  bf16*  w1T    = (bf16*) (ws + 67244032);     //  8 MB
  bf16*  w2T    = (bf16*) (ws + 75636736);     //  8 MB; end = 84025344

  init_kernel<<<32, 256, 0, stream>>>(slot, sel, gate);
  router_kernel<<<2048, 256, 0, stream>>>(x, router_w, router_b, logits);
  topk_kernel<<<32, 256, 0, stream>>>(logits, slot, sel, gate);
  gather_kernel<<<4096, 256, 0, stream>>>(x, sel, h);

  for (int l = 0; l < 2; l++){
    transpose_kernel<<<dim3(48,16), 256, 0, stream>>>(wqkv + (size_t)l*Dc*3*Dc, wqkvT, Dc, 3*Dc);
    transpose_kernel<<<dim3(16,16), 256, 0, stream>>>(wo   + (size_t)l*Dc*Dc,   woT,   Dc, Dc);
    transpose_kernel<<<dim3(64,16), 256, 0, stream>>>(w1   + (size_t)l*Dc*Fc,   w1T,   Dc, Fc);
    transpose_kernel<<<dim3(16,64), 256, 0, stream>>>(w2   + (size_t)l*Fc*Dc,   w2T,   Fc, Dc);

    ln_kernel<<<4096, 256, 0, stream>>>(h, ln1_w + l*Dc, ln1_b + l*Dc, y);
    gemm_bt_kernel<<<dim3(24,32), 256, 0, stream>>>(y, wqkvT, big, nullptr, 4096, 3*Dc, Dc, 0);
    flash_kernel<<<1024, 256, 0, stream>>>(big, y);                       // y now holds attn output o
    gemm_bt64_kernel<<<dim3(16,32), 256, 0, stream>>>(y, woT, nullptr, h, 4096, Dc, Dc, 1);
    ln_kernel<<<4096, 256, 0, stream>>>(h, ln2_w + l*Dc, ln2_b + l*Dc, y);
    gemm_bt_kernel<<<dim3(32,32), 256, 0, stream>>>(y, w1T, big, nullptr, 4096, Fc, Dc, 2);
    gemm_bt64_kernel<<<dim3(16,32), 256, 0, stream>>>(big, w2T, nullptr, h, 4096, Dc, Fc, 1);
  }

  scatter_kernel<<<8192, 256, 0, stream>>>(x, h, gate, slot, out);
}

// Round 2
// 876.991 us; speedup vs baseline: 1.1651x; 1.1167x over previous
//
#include <hip/hip_runtime.h>
#include <cmath>

typedef __bf16 bf16;
typedef __bf16 bf16x2 __attribute__((ext_vector_type(2)));
typedef __bf16 bf16x4 __attribute__((ext_vector_type(4)));
typedef __bf16 bf16x8 __attribute__((ext_vector_type(8)));
typedef float  f32x4  __attribute__((ext_vector_type(4)));

#define AS1(p) ((const __attribute__((address_space(1))) void*)(p))
#define AS3(p) ((__attribute__((address_space(3))) void*)(p))

// problem constants
constexpr int Bc = 2, Tc = 4096, Dc = 1024, Hc = 16, Fc = 4096, Kc = 2048;

// ---------------------------------------------------------------- router (fp32) + init fused
__global__ __launch_bounds__(256) void router_kernel(const float* __restrict__ x,
    const float* __restrict__ rw, const float* __restrict__ rb, float* __restrict__ logits,
    int* __restrict__ slot, int* __restrict__ sel, float* __restrict__ gate){
  int flat = blockIdx.x * 256 + threadIdx.x;       // grid 2048 -> 524288
  if (flat < Bc * Tc) slot[flat] = -1;             // defensive init (no poison survives)
  if (flat < Bc * Kc){ sel[flat] = flat & (Kc - 1); gate[flat] = 0.f; }
  int wv = threadIdx.x >> 6, lane = threadIdx.x & 63;
  int token = blockIdx.x * 4 + wv;                 // 8192 tokens
  const float* xr = x + (size_t)token * Dc;
  float s = 0.f;
#pragma unroll
  for (int i = 0; i < 16; i++){ int d = lane + i*64; s += xr[d] * rw[d]; }
#pragma unroll
  for (int m = 32; m; m >>= 1) s += __shfl_xor(s, m);
  if (lane == 0) logits[token] = s + rb[0];
}

// ---------------------------------------------------------------- top-k by rank counting
__global__ __launch_bounds__(256) void topk_kernel(const float* __restrict__ logits,
    int* __restrict__ slot, int* __restrict__ sel, float* __restrict__ gate){
  __shared__ float lg[Tc];
  int b = blockIdx.x >> 4, seg = blockIdx.x & 15;  // grid 32
  const float* lb = logits + (size_t)b * Tc;
  for (int i = threadIdx.x; i < Tc; i += 256) lg[i] = lb[i];
  __syncthreads();
  int t = seg * 256 + threadIdx.x;
  float v = lg[t];
  int rank = 0;
  for (int j = 0; j < Tc; j++){
    float u = lg[j];
    rank += (u > v) || (u == v && j < t);          // strict total order == JAX top_k
  }
  if (rank < Kc){
    sel [b*Kc + rank] = t;
    gate[b*Kc + rank] = 1.f / (1.f + expf(-v));
    slot[b*Tc + t] = rank;
  }
}

// ---------------------------------------------------------------- gather to fp32 h
__global__ __launch_bounds__(256) void gather_kernel(const float* __restrict__ x,
    const int* __restrict__ sel, float* __restrict__ h){
  int row = blockIdx.x;                            // b*Kc + k, grid 4096
  int b = row >> 11;
  int t = sel[row];
  t = (t < 0) ? 0 : (t >= Tc ? Tc - 1 : t);        // clamp: fault -> wrong answer
  const float* xr = x + ((size_t)b * Tc + t) * Dc;
  float* hr = h + (size_t)row * Dc;
  int d = threadIdx.x * 4;
  *(float4*)(hr + d) = *(const float4*)(xr + d);
}

// ---------------------------------------------------------------- layernorm fp32->bf16
__global__ __launch_bounds__(256) void ln_kernel(const float* __restrict__ h,
    const float* __restrict__ w, const float* __restrict__ bb, bf16* __restrict__ y){
  __shared__ float red[4], red2[4];
  int row = blockIdx.x, t = threadIdx.x;
  int wv = t >> 6, lane = t & 63;
  const float* hr = h + (size_t)row * Dc;
  float4 x4 = *(const float4*)(hr + t*4);
  float s = x4.x + x4.y + x4.z + x4.w;
#pragma unroll
  for (int m = 32; m; m >>= 1) s += __shfl_xor(s, m);
  if (lane == 0) red[wv] = s;
  __syncthreads();
  float mu = (red[0]+red[1]+red[2]+red[3]) * (1.f/Dc);
  float d0 = x4.x-mu, d1 = x4.y-mu, d2 = x4.z-mu, d3 = x4.w-mu;
  float q = d0*d0 + d1*d1 + d2*d2 + d3*d3;
#pragma unroll
  for (int m = 32; m; m >>= 1) q += __shfl_xor(q, m);
  if (lane == 0) red2[wv] = q;
  __syncthreads();
  float var = (red2[0]+red2[1]+red2[2]+red2[3]) * (1.f/Dc);
  float rs = rsqrtf(var + 1e-5f);
  bf16* yr = y + (size_t)row * Dc;
  int d = t * 4;
  float xv[4] = {x4.x, x4.y, x4.z, x4.w};
#pragma unroll
  for (int i = 0; i < 4; i++)
    yr[d+i] = (bf16)((xv[i]-mu) * rs * w[d+i] + bb[d+i]);
}

// ---------------------------------------------------------------- weight transpose fp32 -> bf16 (tile body)
__device__ __forceinline__ void transpose_tile(const float* __restrict__ in,
    bf16* __restrict__ out, int R, int C, int bx, int by, bf16 (*tile)[72]){
  int c0 = bx * 64, r0 = by * 64;
  int t = threadIdx.x;
#pragma unroll
  for (int i = 0; i < 2; i++){
    int ch = t + i*256;
    int row = ch >> 3, col8 = (ch & 7) * 8;
    const float* src = in + (size_t)(r0+row)*C + c0 + col8;
    float4 a = *(const float4*)src;
    float4 b = *(const float4*)(src + 4);
    bf16x8 v;
    v[0]=(bf16)a.x; v[1]=(bf16)a.y; v[2]=(bf16)a.z; v[3]=(bf16)a.w;
    v[4]=(bf16)b.x; v[5]=(bf16)b.y; v[6]=(bf16)b.z; v[7]=(bf16)b.w;
    *(bf16x8*)&tile[row][col8] = v;
  }
  __syncthreads();
#pragma unroll
  for (int i = 0; i < 2; i++){
    int ch = t + i*256;
    int orow = ch >> 3, oc8 = (ch & 7) * 8;
    bf16x8 v;
#pragma unroll
    for (int j = 0; j < 8; j++) v[j] = tile[oc8+j][orow];
    *(bf16x8*)(out + (size_t)(c0+orow)*R + r0 + oc8) = v;
  }
}

// all 4 per-layer weight transposes in one launch (grid 3072): saves 6 dispatch gaps
__global__ __launch_bounds__(256) void transpose4_kernel(
    const float* __restrict__ wqkv, const float* __restrict__ wo,
    const float* __restrict__ w1,   const float* __restrict__ w2,
    bf16* __restrict__ wqkvT, bf16* __restrict__ woT,
    bf16* __restrict__ w1T,   bf16* __restrict__ w2T){
  __shared__ __attribute__((aligned(16))) bf16 tile[64][72];
  int id = blockIdx.x;
  if (id < 768)        transpose_tile(wqkv, wqkvT, Dc, 3*Dc, id % 48,        id / 48,        tile);
  else if (id < 1024){ int t = id - 768;  transpose_tile(wo, woT, Dc, Dc,   t % 16,         t / 16,         tile); }
  else if (id < 2048){ int t = id - 1024; transpose_tile(w1, w1T, Dc, Fc,   t % 64,         t / 64,         tile); }
  else               { int t = id - 2048; transpose_tile(w2, w2T, Fc, Dc,   t % 16,         t / 16,         tile); }
}

// fast gelu (tanh approx == sigmoid form), exp2-based
__device__ __forceinline__ float fast_gelu(float v){
  float u = exp2f(v * (1.f + 0.044715f*v*v) * -2.30220772f);  // 2*0.79788456*log2(e)
  return v * __builtin_amdgcn_rcpf(1.f + u);
}

// ---------------------------------------------------------------- MFMA GEMM 128x128, BK=64
// LDS layout [rows][64] with XOR swizzle: linear slot (r, c16) holds global col-block
// (c16 ^ (r&7)); staged via pre-swizzled global source (rule #21: both-sides-or-neither).
// Halves barrier count vs BK=32 (m233: stage+vmcnt+barrier = ~72% of 2-phase critical path).
// mode 0: Cbf = bf16(acc); mode 1: Cf += acc (fp32 residual); mode 2: Cbf = bf16(gelu(acc))
__global__ __launch_bounds__(256) void gemm_bt_kernel(
    const bf16* __restrict__ A, const bf16* __restrict__ Bt,
    bf16* __restrict__ Cbf, float* __restrict__ Cf,
    int M, int N, int Kd, int mode)
{
  __shared__ __attribute__((aligned(16))) bf16 As[128*64];
  __shared__ __attribute__((aligned(16))) bf16 Bs[128*64];
  const int tid = threadIdx.x;
  const int wv = tid >> 6, lane = tid & 63;
  const int wm = wv & 1, wn = wv >> 1;
  const int quad = lane >> 4, l15 = lane & 15;
  const int m0 = blockIdx.y * 128, n0 = blockIdx.x * 128;
  f32x4 acc[4][4] = {};

  // staging: lane covers row (tid>>3) (+32 per round), global col-block (tid&7)^(row&7)
  const int arow = tid >> 3;
  const int acol = ((tid & 7) ^ (arow & 7)) * 8;
  const bf16* Ag = A  + (size_t)(m0 + arow) * Kd + acol;
  const bf16* Bg = Bt + (size_t)(n0 + arow) * Kd + acol;
  char* AsB = (char*)As;
  char* BsB = (char*)Bs;
  const size_t rstep = (size_t)32 * Kd;

  // swizzled read bases
  const bf16* Ab = As + (size_t)(wm*64 + l15) * 64;
  const bf16* Bb = Bs + (size_t)(wn*64 + l15) * 64;
  const int rx = l15 & 7;

  for (int k0 = 0; k0 < Kd; k0 += 64){
    __syncthreads();
#pragma unroll
    for (int i = 0; i < 4; i++){
      __builtin_amdgcn_global_load_lds(AS1(Ag + i*rstep + k0), AS3(AsB + i*4096 + wv*1024), 16, 0, 0);
      __builtin_amdgcn_global_load_lds(AS1(Bg + i*rstep + k0), AS3(BsB + i*4096 + wv*1024), 16, 0, 0);
    }
    __syncthreads();
#pragma unroll
    for (int s = 0; s < 2; s++){
      const int ax = ((s*4 + quad) ^ rx) * 8;
      bf16x8 af[4], bfr[4];
#pragma unroll
      for (int mt = 0; mt < 4; mt++) af[mt]  = *(const bf16x8*)(Ab + mt*1024 + ax);
#pragma unroll
      for (int nt = 0; nt < 4; nt++) bfr[nt] = *(const bf16x8*)(Bb + nt*1024 + ax);
#pragma unroll
      for (int mt = 0; mt < 4; mt++)
#pragma unroll
        for (int nt = 0; nt < 4; nt++)
          acc[mt][nt] = __builtin_amdgcn_mfma_f32_16x16x32_bf16(af[mt], bfr[nt], acc[mt][nt], 0, 0, 0);
    }
  }
#pragma unroll
  for (int mt = 0; mt < 4; mt++){
    int rr0 = m0 + wm*64 + mt*16 + (lane>>4)*4;
#pragma unroll
    for (int nt = 0; nt < 4; nt++){
      int cc = n0 + wn*64 + nt*16 + (lane&15);
#pragma unroll
      for (int r = 0; r < 4; r++){
        float v = acc[mt][nt][r];
        size_t idx = (size_t)(rr0 + r) * N + cc;
        if (mode == 0)      Cbf[idx] = (bf16)v;
        else if (mode == 1) Cf[idx] += v;
        else                Cbf[idx] = (bf16)fast_gelu(v);
      }
    }
  }
}

// ---------------------------------------------------------------- MFMA GEMM 128x64, BK=64 (N=1024: 2 blocks/CU)
__global__ __launch_bounds__(256) void gemm_bt64_kernel(
    const bf16* __restrict__ A, const bf16* __restrict__ Bt,
    bf16* __restrict__ Cbf, float* __restrict__ Cf,
    int M, int N, int Kd, int mode)
{
  __shared__ __attribute__((aligned(16))) bf16 As[128*64];
  __shared__ __attribute__((aligned(16))) bf16 Bs[64*64];
  const int tid = threadIdx.x;
  const int wv = tid >> 6, lane = tid & 63;
  const int wm = wv >> 1, wn = wv & 1;            // 2x2 waves: wave = 64(m) x 32(n)
  const int quad = lane >> 4, l15 = lane & 15;
  const int m0 = blockIdx.y * 128, n0 = blockIdx.x * 64;
  f32x4 acc[4][2] = {};

  const int arow = tid >> 3;
  const int acol = ((tid & 7) ^ (arow & 7)) * 8;
  const bf16* Ag = A  + (size_t)(m0 + arow) * Kd + acol;
  const bf16* Bg = Bt + (size_t)(n0 + arow) * Kd + acol;
  char* AsB = (char*)As;
  char* BsB = (char*)Bs;
  const size_t rstep = (size_t)32 * Kd;

  const bf16* Ab = As + (size_t)(wm*64 + l15) * 64;
  const bf16* Bb = Bs + (size_t)(wn*32 + l15) * 64;
  const int rx = l15 & 7;

  for (int k0 = 0; k0 < Kd; k0 += 64){
    __syncthreads();
#pragma unroll
    for (int i = 0; i < 4; i++)
      __builtin_amdgcn_global_load_lds(AS1(Ag + i*rstep + k0), AS3(AsB + i*4096 + wv*1024), 16, 0, 0);
#pragma unroll
    for (int i = 0; i < 2; i++)
      __builtin_amdgcn_global_load_lds(AS1(Bg + i*rstep + k0), AS3(BsB + i*4096 + wv*1024), 16, 0, 0);
    __syncthreads();
#pragma unroll
    for (int s = 0; s < 2; s++){
      const int ax = ((s*4 + quad) ^ rx) * 8;
      bf16x8 af[4], bfr[2];
#pragma unroll
      for (int mt = 0; mt < 4; mt++) af[mt]  = *(const bf16x8*)(Ab + mt*1024 + ax);
#pragma unroll
      for (int nt = 0; nt < 2; nt++) bfr[nt] = *(const bf16x8*)(Bb + nt*1024 + ax);
#pragma unroll
      for (int mt = 0; mt < 4; mt++)
#pragma unroll
        for (int nt = 0; nt < 2; nt++)
          acc[mt][nt] = __builtin_amdgcn_mfma_f32_16x16x32_bf16(af[mt], bfr[nt], acc[mt][nt], 0, 0, 0);
    }
  }
#pragma unroll
  for (int mt = 0; mt < 4; mt++){
    int rr0 = m0 + wm*64 + mt*16 + (lane>>4)*4;
#pragma unroll
    for (int nt = 0; nt < 2; nt++){
      int cc = n0 + wn*32 + nt*16 + (lane&15);
#pragma unroll
      for (int r = 0; r < 4; r++){
        float v = acc[mt][nt][r];
        size_t idx = (size_t)(rr0 + r) * N + cc;
        if (mode == 0)      Cbf[idx] = (bf16)v;
        else if (mode == 1) Cf[idx] += v;
        else                Cbf[idx] = (bf16)fast_gelu(v);
      }
    }
  }
}

// ---------------------------------------------------------------- flash attention v4 (unchanged this round)
// grid 1024 = 32 qtiles x 16 heads x 2 batch; 256 threads; wave owns 16 q-rows.
__global__ __launch_bounds__(256) void flash_kernel(const bf16* __restrict__ qkv, bf16* __restrict__ o){
  __shared__ __attribute__((aligned(16))) bf16 Ks[64][72];
  __shared__ __attribute__((aligned(16))) bf16 Vt[64*64];
  __shared__ __attribute__((aligned(16))) bf16 Pt[4][64][16];  // per-wave P, transposed [kcol][qrow]
  const int tid = threadIdx.x, wv = tid >> 6, lane = tid & 63;
  const int quad = lane >> 4, l15 = lane & 15;
  const int bid = blockIdx.x;
  const int qt = bid & 31, hh = (bid >> 5) & 15, b = bid >> 9;
  const int q0 = qt * 64;
  const size_t base = (size_t)b * Kc * (3*Dc);
  const float SC2 = 0.125f * 1.44269504f;          // 1/sqrt(64) * log2(e)

  const int sp8 = (tid & 7) * 8;                   // d-col group for staging
  const int kr0 = tid >> 3, kr1 = kr0 + 32;        // K staging rows
  const int vr0 = (tid >> 3) * 2;                  // V staging rows (pair vr0, vr0+1)
  const int vg = vr0 >> 3, vlo = vr0 & 7, vsw = sp8 >> 3;

  // Q direct to registers (A-frag)
  bf16x8 qf[2];
  {
    const bf16* qr = qkv + base + (size_t)(q0 + wv*16 + l15)*(3*Dc) + hh*64 + quad*8;
    qf[0] = *(const bf16x8*)(qr);
    qf[1] = *(const bf16x8*)(qr + 32);
  }

  // prefetch K/V tile 0
  const bf16* kp0 = qkv + base + (size_t)kr0*(3*Dc) +   Dc + hh*64 + sp8;
  const bf16* kp1 = qkv + base + (size_t)kr1*(3*Dc) +   Dc + hh*64 + sp8;
  const bf16* vp0 = qkv + base + (size_t)vr0*(3*Dc) + 2*Dc + hh*64 + sp8;
  const bf16* vp1 = vp0 + 3*Dc;
  bf16x8 kpre0 = *(const bf16x8*)kp0;
  bf16x8 kpre1 = *(const bf16x8*)kp1;
  bf16x8 vpre0 = *(const bf16x8*)vp0;
  bf16x8 vpre1 = *(const bf16x8*)vp1;
  const int TSTRIDE = 64 * 3 * Dc;

  // ones B-frag: column 0 of the virtual 5th V tile
  bf16x8 onesf;
#pragma unroll
  for (int j = 0; j < 8; j++) onesf[j] = (bf16)(l15 == 0 ? 1.f : 0.f);

  f32x4 oacc[4] = {};
  f32x4 oacc5 = {};                                 // row-sums of P (alpha-chained)
  float mrow[4];
#pragma unroll
  for (int r = 0; r < 4; r++) mrow[r] = -1e30f;

  for (int kt = 0; kt < 32; kt++){
    __syncthreads();                               // prev tile's readers done
    // stage K (b128) and V (packed kv-pairs, b32)
    *(bf16x8*)&Ks[kr0][sp8] = kpre0;
    *(bf16x8*)&Ks[kr1][sp8] = kpre1;
#pragma unroll
    for (int j = 0; j < 8; j++){
      bf16x2 pr; pr[0] = vpre0[j]; pr[1] = vpre1[j];
      *(bf16x2*)&Vt[(sp8 + j)*64 + ((vg ^ j ^ vsw) << 3) + vlo] = pr;
    }
    __syncthreads();
    // prefetch next tile (overlaps compute below)
    if (kt < 31){
      kp0 += TSTRIDE; kp1 += TSTRIDE; vp0 += TSTRIDE; vp1 += TSTRIDE;
      kpre0 = *(const bf16x8*)kp0;
      kpre1 = *(const bf16x8*)kp1;
      vpre0 = *(const bf16x8*)vp0;
      vpre1 = *(const bf16x8*)vp1;
    }
    // S = Q K^T
    f32x4 sacc[4] = {};
    __builtin_amdgcn_s_setprio(1);
#pragma unroll
    for (int nt = 0; nt < 4; nt++)
#pragma unroll
      for (int s = 0; s < 2; s++){
        bf16x8 kf = *(const bf16x8*)&Ks[nt*16 + l15][s*32 + quad*8];
        sacc[nt] = __builtin_amdgcn_mfma_f32_16x16x32_bf16(qf[s], kf, sacc[nt], 0, 0, 0);
      }
    __builtin_amdgcn_s_setprio(0);
    // ---- online softmax, exp2 domain, deferred rescale (THR = 8) ----
    float lm[4];
#pragma unroll
    for (int r = 0; r < 4; r++)
      lm[r] = fmaxf(fmaxf(sacc[0][r], sacc[1][r]), fmaxf(sacc[2][r], sacc[3][r]));
    bool ok = true;
#pragma unroll
    for (int r = 0; r < 4; r++) ok = ok && (lm[r] * SC2 <= mrow[r] + 8.f);
    if (!__all((int)ok)){
      // slow path: full 16-lane max reduce + alpha rescale (tile 0 + rare growth)
#pragma unroll
      for (int r = 0; r < 4; r++){
        float mx = lm[r];
#pragma unroll
        for (int m = 1; m < 16; m <<= 1) mx = fmaxf(mx, __shfl_xor(mx, m));
        float nm = fmaxf(mrow[r], mx * SC2);
        float alpha = exp2f(mrow[r] - nm);
        mrow[r] = nm;
#pragma unroll
        for (int nt = 0; nt < 4; nt++) oacc[nt][r] *= alpha;
        oacc5[r] *= alpha;
      }
    }
    // P = exp2(S*SC2 - mrow), stored transposed: Pt[wv][k][q], b64 packed stores
#pragma unroll
    for (int nt = 0; nt < 4; nt++){
      bf16x4 w;
#pragma unroll
      for (int r = 0; r < 4; r++) w[r] = (bf16)exp2f(fmaf(sacc[nt][r], SC2, -mrow[r]));
      *(bf16x4*)&Pt[wv][nt*16 + l15][quad*4] = w;
    }
    // A-frag via HW transpose read: pf[s][j] = Pt[wv][s*32+quad*8+j][l15]
    bf16x8 pf[2];
    {
      bf16x4 t00, t01, t10, t11;
      const bf16* pr0 = &Pt[wv][     quad*8][l15];
      const bf16* pr1 = &Pt[wv][32 + quad*8][l15];
      asm volatile("ds_read_b64_tr_b16 %0, %1"            : "=v"(t00) : "v"(AS3(pr0)) : "memory");
      asm volatile("ds_read_b64_tr_b16 %0, %1 offset:128" : "=v"(t01) : "v"(AS3(pr0)) : "memory");
      asm volatile("ds_read_b64_tr_b16 %0, %1"            : "=v"(t10) : "v"(AS3(pr1)) : "memory");
      asm volatile("ds_read_b64_tr_b16 %0, %1 offset:128" : "=v"(t11) : "v"(AS3(pr1)) : "memory");
      asm volatile("s_waitcnt lgkmcnt(0)" ::: "memory");   // rule #18 fence
      __builtin_amdgcn_sched_barrier(0);
#pragma unroll
      for (int j = 0; j < 4; j++){
        pf[0][j] = t00[j]; pf[0][j+4] = t01[j];
        pf[1][j] = t10[j]; pf[1][j+4] = t11[j];
      }
    }
    // PV with swizzled Vt reads + ones-column row-sum
    __builtin_amdgcn_s_setprio(1);
#pragma unroll
    for (int nt = 0; nt < 4; nt++){
      int d = nt*16 + l15;
      int sw = (d & 7) ^ ((d >> 3) & 7);
#pragma unroll
      for (int s = 0; s < 2; s++){
        bf16x8 vf = *(const bf16x8*)&Vt[d*64 + (((s*4 + quad) ^ sw) << 3)];
        oacc[nt] = __builtin_amdgcn_mfma_f32_16x16x32_bf16(pf[s], vf, oacc[nt], 0, 0, 0);
      }
    }
    oacc5 = __builtin_amdgcn_mfma_f32_16x16x32_bf16(pf[0], onesf, oacc5, 0, 0, 0);
    oacc5 = __builtin_amdgcn_mfma_f32_16x16x32_bf16(pf[1], onesf, oacc5, 0, 0, 0);
    __builtin_amdgcn_s_setprio(0);
  }
  // epilogue: l lives in lane (quad*16 + 0) of each quad-group, col 0
#pragma unroll
  for (int r = 0; r < 4; r++){
    float l = __shfl(oacc5[r], lane & 48);
    float inv = __builtin_amdgcn_rcpf(l);
    int row = q0 + wv*16 + quad*4 + r;
#pragma unroll
    for (int nt = 0; nt < 4; nt++)
      o[((size_t)b*Kc + row)*Dc + hh*64 + nt*16 + l15] = (bf16)(oacc[nt][r] * inv);
  }
}

// ---------------------------------------------------------------- scatter-add to fp32 output
__global__ __launch_bounds__(256) void scatter_kernel(const float* __restrict__ x,
    const float* __restrict__ h, const float* __restrict__ gate,
    const int* __restrict__ slot, float* __restrict__ out){
  int row = blockIdx.x;                       // b*Tc + t, grid 8192
  int b = row >> 12;
  int d = threadIdx.x * 4;
  const float* xr = x + (size_t)row * Dc;
  float* orow = out + (size_t)row * Dc;
  int sl = slot[row];
  if (sl >= 0 && sl < Kc){
    float g = gate[b*Kc + sl];
    const float* hr = h + ((size_t)b*Kc + sl) * Dc;
    float4 xv = *(const float4*)(xr + d);
    float4 hv = *(const float4*)(hr + d);
    float4 ov = { xv.x + g*hv.x, xv.y + g*hv.y, xv.z + g*hv.z, xv.w + g*hv.w };
    *(float4*)(orow + d) = ov;
  } else {
    *(float4*)(orow + d) = *(const float4*)(xr + d);
  }
}

// ---------------------------------------------------------------- launch
extern "C" void kernel_launch(void* const* d_in, const int* in_sizes, int n_in,
                              void* d_out, int out_size, void* d_ws, size_t ws_size,
                              hipStream_t stream)
{
  const float* x        = (const float*)d_in[0];
  const float* router_w = (const float*)d_in[1];
  const float* router_b = (const float*)d_in[2];
  const float* ln1_w    = (const float*)d_in[3];
  const float* ln1_b    = (const float*)d_in[4];
  const float* wqkv     = (const float*)d_in[5];
  const float* wo       = (const float*)d_in[6];
  const float* ln2_w    = (const float*)d_in[7];
  const float* ln2_b    = (const float*)d_in[8];
  const float* w1       = (const float*)d_in[9];
  const float* w2       = (const float*)d_in[10];
  float* out = (float*)d_out;

  // workspace layout (bytes), 4 KB pad between regions
  char* ws = (char*)d_ws;
  if (ws_size < 84029440u) return;
  float* logits = (float*)(ws + 0);            //  32768
  int*   slot   = (int*)  (ws + 36864);        //  32768
  int*   sel    = (int*)  (ws + 73728);        //  16384
  float* gate   = (float*)(ws + 94208);        //  16384
  float* h      = (float*)(ws + 114688);       //  16 MB fp32 residual stream [4096,1024]
  bf16*  y      = (bf16*) (ws + 16896000);     //  8 MB  (aliases attention output o)
  bf16*  big    = (bf16*) (ws + 25288704);     //  32 MB (qkv [4096,3072] / gelu [4096,4096])
  bf16*  wqkvT  = (bf16*) (ws + 58847232);     //  6 MB
  bf16*  woT    = (bf16*) (ws + 65142784);     //  2 MB
  bf16*  w1T    = (bf16*) (ws + 67244032);     //  8 MB
  bf16*  w2T    = (bf16*) (ws + 75636736);     //  8 MB; end = 84025344

  router_kernel<<<2048, 256, 0, stream>>>(x, router_w, router_b, logits, slot, sel, gate);
  topk_kernel<<<32, 256, 0, stream>>>(logits, slot, sel, gate);
  gather_kernel<<<4096, 256, 0, stream>>>(x, sel, h);

  for (int l = 0; l < 2; l++){
    transpose4_kernel<<<3072, 256, 0, stream>>>(
        wqkv + (size_t)l*Dc*3*Dc, wo + (size_t)l*Dc*Dc,
        w1 + (size_t)l*Dc*Fc,     w2 + (size_t)l*Fc*Dc,
        wqkvT, woT, w1T, w2T);

    ln_kernel<<<4096, 256, 0, stream>>>(h, ln1_w + l*Dc, ln1_b + l*Dc, y);
    gemm_bt_kernel<<<dim3(24,32), 256, 0, stream>>>(y, wqkvT, big, nullptr, 4096, 3*Dc, Dc, 0);
    flash_kernel<<<1024, 256, 0, stream>>>(big, y);                       // y now holds attn output o
    gemm_bt64_kernel<<<dim3(16,32), 256, 0, stream>>>(y, woT, nullptr, h, 4096, Dc, Dc, 1);
    ln_kernel<<<4096, 256, 0, stream>>>(h, ln2_w + l*Dc, ln2_b + l*Dc, y);
    gemm_bt_kernel<<<dim3(32,32), 256, 0, stream>>>(y, w1T, big, nullptr, 4096, Fc, Dc, 2);
    gemm_bt64_kernel<<<dim3(16,32), 256, 0, stream>>>(big, w2T, nullptr, h, 4096, Dc, Fc, 1);
  }

  scatter_kernel<<<8192, 256, 0, stream>>>(x, h, gate, slot, out);
}

// Round 3
// 821.523 us; speedup vs baseline: 1.2438x; 1.0675x over previous
//
#include <hip/hip_runtime.h>
#include <cmath>

typedef __bf16 bf16;
typedef __bf16 bf16x2 __attribute__((ext_vector_type(2)));
typedef __bf16 bf16x4 __attribute__((ext_vector_type(4)));
typedef __bf16 bf16x8 __attribute__((ext_vector_type(8)));
typedef float  f32x4  __attribute__((ext_vector_type(4)));

#define AS1(p) ((const __attribute__((address_space(1))) void*)(p))
#define AS3(p) ((__attribute__((address_space(3))) void*)(p))

// problem constants
constexpr int Bc = 2, Tc = 4096, Dc = 1024, Hc = 16, Fc = 4096, Kc = 2048;

// ---------------------------------------------------------------- router (fp32) + init fused
__global__ __launch_bounds__(256) void router_kernel(const float* __restrict__ x,
    const float* __restrict__ rw, const float* __restrict__ rb, float* __restrict__ logits,
    int* __restrict__ slot, int* __restrict__ sel, float* __restrict__ gate){
  int flat = blockIdx.x * 256 + threadIdx.x;       // grid 2048 -> 524288
  if (flat < Bc * Tc) slot[flat] = -1;             // defensive init (no poison survives)
  if (flat < Bc * Kc){ sel[flat] = flat & (Kc - 1); gate[flat] = 0.f; }
  int wv = threadIdx.x >> 6, lane = threadIdx.x & 63;
  int token = blockIdx.x * 4 + wv;                 // 8192 tokens
  const float* xr = x + (size_t)token * Dc;
  float s = 0.f;
#pragma unroll
  for (int i = 0; i < 16; i++){ int d = lane + i*64; s += xr[d] * rw[d]; }
#pragma unroll
  for (int m = 32; m; m >>= 1) s += __shfl_xor(s, m);
  if (lane == 0) logits[token] = s + rb[0];
}

// ---------------------------------------------------------------- top-k by rank counting (v2: parallelized)
// R1 profile: 106 us at 1.4% occupancy, 3% VALUBusy -- 32 blocks x serial-4096 scan was
// latency-starved. v2: 256 blocks, 8 lanes per token each scanning a 512-chunk (float4),
// 3-step shfl_xor partial-rank reduce. Identical strict-total-order rank arithmetic.
__global__ __launch_bounds__(256) void topk_kernel(const float* __restrict__ logits,
    int* __restrict__ slot, int* __restrict__ sel, float* __restrict__ gate){
  __shared__ float lg[Tc];
  int b = blockIdx.x >> 7, seg = blockIdx.x & 127;  // grid 256
  const float* lb = logits + (size_t)b * Tc;
#pragma unroll
  for (int i = 0; i < 4; i++)
    *(float4*)&lg[(threadIdx.x + i*256)*4] = *(const float4*)&lb[(threadIdx.x + i*256)*4];
  __syncthreads();
  int t = seg * 32 + (threadIdx.x >> 3);            // this 8-lane group's token
  int c = threadIdx.x & 7;                           // chunk id within the scan
  float v = lg[t];
  int rank = 0;
#pragma unroll 4
  for (int j4 = c*128; j4 < c*128 + 128; j4++){
    float4 u4 = *(const float4*)&lg[j4*4];
    int j = j4*4;
    rank += (u4.x > v) || (u4.x == v && (j+0) < t);
    rank += (u4.y > v) || (u4.y == v && (j+1) < t);
    rank += (u4.z > v) || (u4.z == v && (j+2) < t);
    rank += (u4.w > v) || (u4.w == v && (j+3) < t);
  }
  rank += __shfl_xor(rank, 1);                       // 8-lane groups are wave-contiguous
  rank += __shfl_xor(rank, 2);
  rank += __shfl_xor(rank, 4);
  if (c == 0 && rank < Kc){
    sel [b*Kc + rank] = t;
    gate[b*Kc + rank] = 1.f / (1.f + expf(-v));
    slot[b*Tc + t] = rank;
  }
}

// ---------------------------------------------------------------- gather to fp32 h
__global__ __launch_bounds__(256) void gather_kernel(const float* __restrict__ x,
    const int* __restrict__ sel, float* __restrict__ h){
  int row = blockIdx.x;                            // b*Kc + k, grid 4096
  int b = row >> 11;
  int t = sel[row];
  t = (t < 0) ? 0 : (t >= Tc ? Tc - 1 : t);        // clamp: fault -> wrong answer
  const float* xr = x + ((size_t)b * Tc + t) * Dc;
  float* hr = h + (size_t)row * Dc;
  int d = threadIdx.x * 4;
  *(float4*)(hr + d) = *(const float4*)(xr + d);
}

// ---------------------------------------------------------------- layernorm fp32->bf16
__global__ __launch_bounds__(256) void ln_kernel(const float* __restrict__ h,
    const float* __restrict__ w, const float* __restrict__ bb, bf16* __restrict__ y){
  __shared__ float red[4], red2[4];
  int row = blockIdx.x, t = threadIdx.x;
  int wv = t >> 6, lane = t & 63;
  const float* hr = h + (size_t)row * Dc;
  float4 x4 = *(const float4*)(hr + t*4);
  float s = x4.x + x4.y + x4.z + x4.w;
#pragma unroll
  for (int m = 32; m; m >>= 1) s += __shfl_xor(s, m);
  if (lane == 0) red[wv] = s;
  __syncthreads();
  float mu = (red[0]+red[1]+red[2]+red[3]) * (1.f/Dc);
  float d0 = x4.x-mu, d1 = x4.y-mu, d2 = x4.z-mu, d3 = x4.w-mu;
  float q = d0*d0 + d1*d1 + d2*d2 + d3*d3;
#pragma unroll
  for (int m = 32; m; m >>= 1) q += __shfl_xor(q, m);
  if (lane == 0) red2[wv] = q;
  __syncthreads();
  float var = (red2[0]+red2[1]+red2[2]+red2[3]) * (1.f/Dc);
  float rs = rsqrtf(var + 1e-5f);
  bf16* yr = y + (size_t)row * Dc;
  int d = t * 4;
  float xv[4] = {x4.x, x4.y, x4.z, x4.w};
#pragma unroll
  for (int i = 0; i < 4; i++)
    yr[d+i] = (bf16)((xv[i]-mu) * rs * w[d+i] + bb[d+i]);
}

// ---------------------------------------------------------------- weight transpose fp32 -> bf16 (tile body)
__device__ __forceinline__ void transpose_tile(const float* __restrict__ in,
    bf16* __restrict__ out, int R, int C, int bx, int by, bf16 (*tile)[72]){
  int c0 = bx * 64, r0 = by * 64;
  int t = threadIdx.x;
#pragma unroll
  for (int i = 0; i < 2; i++){
    int ch = t + i*256;
    int row = ch >> 3, col8 = (ch & 7) * 8;
    const float* src = in + (size_t)(r0+row)*C + c0 + col8;
    float4 a = *(const float4*)src;
    float4 b = *(const float4*)(src + 4);
    bf16x8 v;
    v[0]=(bf16)a.x; v[1]=(bf16)a.y; v[2]=(bf16)a.z; v[3]=(bf16)a.w;
    v[4]=(bf16)b.x; v[5]=(bf16)b.y; v[6]=(bf16)b.z; v[7]=(bf16)b.w;
    *(bf16x8*)&tile[row][col8] = v;
  }
  __syncthreads();
#pragma unroll
  for (int i = 0; i < 2; i++){
    int ch = t + i*256;
    int orow = ch >> 3, oc8 = (ch & 7) * 8;
    bf16x8 v;
#pragma unroll
    for (int j = 0; j < 8; j++) v[j] = tile[oc8+j][orow];
    *(bf16x8*)(out + (size_t)(c0+orow)*R + r0 + oc8) = v;
  }
}

// all 4 per-layer weight transposes in one launch (grid 3072)
__global__ __launch_bounds__(256) void transpose4_kernel(
    const float* __restrict__ wqkv, const float* __restrict__ wo,
    const float* __restrict__ w1,   const float* __restrict__ w2,
    bf16* __restrict__ wqkvT, bf16* __restrict__ woT,
    bf16* __restrict__ w1T,   bf16* __restrict__ w2T){
  __shared__ __attribute__((aligned(16))) bf16 tile[64][72];
  int id = blockIdx.x;
  if (id < 768)        transpose_tile(wqkv, wqkvT, Dc, 3*Dc, id % 48,        id / 48,        tile);
  else if (id < 1024){ int t = id - 768;  transpose_tile(wo, woT, Dc, Dc,   t % 16,         t / 16,         tile); }
  else if (id < 2048){ int t = id - 1024; transpose_tile(w1, w1T, Dc, Fc,   t % 64,         t / 64,         tile); }
  else               { int t = id - 2048; transpose_tile(w2, w2T, Fc, Dc,   t % 16,         t / 16,         tile); }
}

// fast gelu (tanh approx == sigmoid form), exp2-based
__device__ __forceinline__ float fast_gelu(float v){
  float u = exp2f(v * (1.f + 0.044715f*v*v) * -2.30220772f);  // 2*0.79788456*log2(e)
  return v * __builtin_amdgcn_rcpf(1.f + u);
}

// ---------------------------------------------------------------- MFMA GEMM 128x128, BK=64
// LDS layout [rows][64] with XOR swizzle: linear slot (r, c16) holds global col-block
// (c16 ^ (r&7)); staged via pre-swizzled global source (rule #21: both-sides-or-neither).
// mode 0: Cbf = bf16(acc); mode 1: Cf += acc (fp32 residual); mode 2: Cbf = bf16(gelu(acc))
__global__ __launch_bounds__(256) void gemm_bt_kernel(
    const bf16* __restrict__ A, const bf16* __restrict__ Bt,
    bf16* __restrict__ Cbf, float* __restrict__ Cf,
    int M, int N, int Kd, int mode)
{
  __shared__ __attribute__((aligned(16))) bf16 As[128*64];
  __shared__ __attribute__((aligned(16))) bf16 Bs[128*64];
  const int tid = threadIdx.x;
  const int wv = tid >> 6, lane = tid & 63;
  const int wm = wv & 1, wn = wv >> 1;
  const int quad = lane >> 4, l15 = lane & 15;
  const int m0 = blockIdx.y * 128, n0 = blockIdx.x * 128;
  f32x4 acc[4][4] = {};

  const int arow = tid >> 3;
  const int acol = ((tid & 7) ^ (arow & 7)) * 8;
  const bf16* Ag = A  + (size_t)(m0 + arow) * Kd + acol;
  const bf16* Bg = Bt + (size_t)(n0 + arow) * Kd + acol;
  char* AsB = (char*)As;
  char* BsB = (char*)Bs;
  const size_t rstep = (size_t)32 * Kd;

  const bf16* Ab = As + (size_t)(wm*64 + l15) * 64;
  const bf16* Bb = Bs + (size_t)(wn*64 + l15) * 64;
  const int rx = l15 & 7;

  for (int k0 = 0; k0 < Kd; k0 += 64){
    __syncthreads();
#pragma unroll
    for (int i = 0; i < 4; i++){
      __builtin_amdgcn_global_load_lds(AS1(Ag + i*rstep + k0), AS3(AsB + i*4096 + wv*1024), 16, 0, 0);
      __builtin_amdgcn_global_load_lds(AS1(Bg + i*rstep + k0), AS3(BsB + i*4096 + wv*1024), 16, 0, 0);
    }
    __syncthreads();
#pragma unroll
    for (int s = 0; s < 2; s++){
      const int ax = ((s*4 + quad) ^ rx) * 8;
      bf16x8 af[4], bfr[4];
#pragma unroll
      for (int mt = 0; mt < 4; mt++) af[mt]  = *(const bf16x8*)(Ab + mt*1024 + ax);
#pragma unroll
      for (int nt = 0; nt < 4; nt++) bfr[nt] = *(const bf16x8*)(Bb + nt*1024 + ax);
#pragma unroll
      for (int mt = 0; mt < 4; mt++)
#pragma unroll
        for (int nt = 0; nt < 4; nt++)
          acc[mt][nt] = __builtin_amdgcn_mfma_f32_16x16x32_bf16(af[mt], bfr[nt], acc[mt][nt], 0, 0, 0);
    }
  }
#pragma unroll
  for (int mt = 0; mt < 4; mt++){
    int rr0 = m0 + wm*64 + mt*16 + (lane>>4)*4;
#pragma unroll
    for (int nt = 0; nt < 4; nt++){
      int cc = n0 + wn*64 + nt*16 + (lane&15);
#pragma unroll
      for (int r = 0; r < 4; r++){
        float v = acc[mt][nt][r];
        size_t idx = (size_t)(rr0 + r) * N + cc;
        if (mode == 0)      Cbf[idx] = (bf16)v;
        else if (mode == 1) Cf[idx] += v;
        else                Cbf[idx] = (bf16)fast_gelu(v);
      }
    }
  }
}

// ---------------------------------------------------------------- MFMA GEMM 128x64, BK=64 (N=1024: 2 blocks/CU)
__global__ __launch_bounds__(256) void gemm_bt64_kernel(
    const bf16* __restrict__ A, const bf16* __restrict__ Bt,
    bf16* __restrict__ Cbf, float* __restrict__ Cf,
    int M, int N, int Kd, int mode)
{
  __shared__ __attribute__((aligned(16))) bf16 As[128*64];
  __shared__ __attribute__((aligned(16))) bf16 Bs[64*64];
  const int tid = threadIdx.x;
  const int wv = tid >> 6, lane = tid & 63;
  const int wm = wv >> 1, wn = wv & 1;            // 2x2 waves: wave = 64(m) x 32(n)
  const int quad = lane >> 4, l15 = lane & 15;
  const int m0 = blockIdx.y * 128, n0 = blockIdx.x * 64;
  f32x4 acc[4][2] = {};

  const int arow = tid >> 3;
  const int acol = ((tid & 7) ^ (arow & 7)) * 8;
  const bf16* Ag = A  + (size_t)(m0 + arow) * Kd + acol;
  const bf16* Bg = Bt + (size_t)(n0 + arow) * Kd + acol;
  char* AsB = (char*)As;
  char* BsB = (char*)Bs;
  const size_t rstep = (size_t)32 * Kd;

  const bf16* Ab = As + (size_t)(wm*64 + l15) * 64;
  const bf16* Bb = Bs + (size_t)(wn*32 + l15) * 64;
  const int rx = l15 & 7;

  for (int k0 = 0; k0 < Kd; k0 += 64){
    __syncthreads();
#pragma unroll
    for (int i = 0; i < 4; i++)
      __builtin_amdgcn_global_load_lds(AS1(Ag + i*rstep + k0), AS3(AsB + i*4096 + wv*1024), 16, 0, 0);
#pragma unroll
    for (int i = 0; i < 2; i++)
      __builtin_amdgcn_global_load_lds(AS1(Bg + i*rstep + k0), AS3(BsB + i*4096 + wv*1024), 16, 0, 0);
    __syncthreads();
#pragma unroll
    for (int s = 0; s < 2; s++){
      const int ax = ((s*4 + quad) ^ rx) * 8;
      bf16x8 af[4], bfr[2];
#pragma unroll
      for (int mt = 0; mt < 4; mt++) af[mt]  = *(const bf16x8*)(Ab + mt*1024 + ax);
#pragma unroll
      for (int nt = 0; nt < 2; nt++) bfr[nt] = *(const bf16x8*)(Bb + nt*1024 + ax);
#pragma unroll
      for (int mt = 0; mt < 4; mt++)
#pragma unroll
        for (int nt = 0; nt < 2; nt++)
          acc[mt][nt] = __builtin_amdgcn_mfma_f32_16x16x32_bf16(af[mt], bfr[nt], acc[mt][nt], 0, 0, 0);
    }
  }
#pragma unroll
  for (int mt = 0; mt < 4; mt++){
    int rr0 = m0 + wm*64 + mt*16 + (lane>>4)*4;
#pragma unroll
    for (int nt = 0; nt < 2; nt++){
      int cc = n0 + wn*32 + nt*16 + (lane&15);
#pragma unroll
      for (int r = 0; r < 4; r++){
        float v = acc[mt][nt][r];
        size_t idx = (size_t)(rr0 + r) * N + cc;
        if (mode == 0)      Cbf[idx] = (bf16)v;
        else if (mode == 1) Cf[idx] += v;
        else                Cbf[idx] = (bf16)fast_gelu(v);
      }
    }
  }
}

// ---------------------------------------------------------------- flash attention v4 (unchanged this round)
// grid 1024 = 32 qtiles x 16 heads x 2 batch; 256 threads; wave owns 16 q-rows.
__global__ __launch_bounds__(256) void flash_kernel(const bf16* __restrict__ qkv, bf16* __restrict__ o){
  __shared__ __attribute__((aligned(16))) bf16 Ks[64][72];
  __shared__ __attribute__((aligned(16))) bf16 Vt[64*64];
  __shared__ __attribute__((aligned(16))) bf16 Pt[4][64][16];  // per-wave P, transposed [kcol][qrow]
  const int tid = threadIdx.x, wv = tid >> 6, lane = tid & 63;
  const int quad = lane >> 4, l15 = lane & 15;
  const int bid = blockIdx.x;
  const int qt = bid & 31, hh = (bid >> 5) & 15, b = bid >> 9;
  const int q0 = qt * 64;
  const size_t base = (size_t)b * Kc * (3*Dc);
  const float SC2 = 0.125f * 1.44269504f;          // 1/sqrt(64) * log2(e)

  const int sp8 = (tid & 7) * 8;                   // d-col group for staging
  const int kr0 = tid >> 3, kr1 = kr0 + 32;        // K staging rows
  const int vr0 = (tid >> 3) * 2;                  // V staging rows (pair vr0, vr0+1)
  const int vg = vr0 >> 3, vlo = vr0 & 7, vsw = sp8 >> 3;

  // Q direct to registers (A-frag)
  bf16x8 qf[2];
  {
    const bf16* qr = qkv + base + (size_t)(q0 + wv*16 + l15)*(3*Dc) + hh*64 + quad*8;
    qf[0] = *(const bf16x8*)(qr);
    qf[1] = *(const bf16x8*)(qr + 32);
  }

  // prefetch K/V tile 0
  const bf16* kp0 = qkv + base + (size_t)kr0*(3*Dc) +   Dc + hh*64 + sp8;
  const bf16* kp1 = qkv + base + (size_t)kr1*(3*Dc) +   Dc + hh*64 + sp8;
  const bf16* vp0 = qkv + base + (size_t)vr0*(3*Dc) + 2*Dc + hh*64 + sp8;
  const bf16* vp1 = vp0 + 3*Dc;
  bf16x8 kpre0 = *(const bf16x8*)kp0;
  bf16x8 kpre1 = *(const bf16x8*)kp1;
  bf16x8 vpre0 = *(const bf16x8*)vp0;
  bf16x8 vpre1 = *(const bf16x8*)vp1;
  const int TSTRIDE = 64 * 3 * Dc;

  // ones B-frag: column 0 of the virtual 5th V tile
  bf16x8 onesf;
#pragma unroll
  for (int j = 0; j < 8; j++) onesf[j] = (bf16)(l15 == 0 ? 1.f : 0.f);

  f32x4 oacc[4] = {};
  f32x4 oacc5 = {};                                 // row-sums of P (alpha-chained)
  float mrow[4];
#pragma unroll
  for (int r = 0; r < 4; r++) mrow[r] = -1e30f;

  for (int kt = 0; kt < 32; kt++){
    __syncthreads();                               // prev tile's readers done
    // stage K (b128) and V (packed kv-pairs, b32)
    *(bf16x8*)&Ks[kr0][sp8] = kpre0;
    *(bf16x8*)&Ks[kr1][sp8] = kpre1;
#pragma unroll
    for (int j = 0; j < 8; j++){
      bf16x2 pr; pr[0] = vpre0[j]; pr[1] = vpre1[j];
      *(bf16x2*)&Vt[(sp8 + j)*64 + ((vg ^ j ^ vsw) << 3) + vlo] = pr;
    }
    __syncthreads();
    // prefetch next tile (overlaps compute below)
    if (kt < 31){
      kp0 += TSTRIDE; kp1 += TSTRIDE; vp0 += TSTRIDE; vp1 += TSTRIDE;
      kpre0 = *(const bf16x8*)kp0;
      kpre1 = *(const bf16x8*)kp1;
      vpre0 = *(const bf16x8*)vp0;
      vpre1 = *(const bf16x8*)vp1;
    }
    // S = Q K^T
    f32x4 sacc[4] = {};
    __builtin_amdgcn_s_setprio(1);
#pragma unroll
    for (int nt = 0; nt < 4; nt++)
#pragma unroll
      for (int s = 0; s < 2; s++){
        bf16x8 kf = *(const bf16x8*)&Ks[nt*16 + l15][s*32 + quad*8];
        sacc[nt] = __builtin_amdgcn_mfma_f32_16x16x32_bf16(qf[s], kf, sacc[nt], 0, 0, 0);
      }
    __builtin_amdgcn_s_setprio(0);
    // ---- online softmax, exp2 domain, deferred rescale (THR = 8) ----
    float lm[4];
#pragma unroll
    for (int r = 0; r < 4; r++)
      lm[r] = fmaxf(fmaxf(sacc[0][r], sacc[1][r]), fmaxf(sacc[2][r], sacc[3][r]));
    bool ok = true;
#pragma unroll
    for (int r = 0; r < 4; r++) ok = ok && (lm[r] * SC2 <= mrow[r] + 8.f);
    if (!__all((int)ok)){
      // slow path: full 16-lane max reduce + alpha rescale (tile 0 + rare growth)
#pragma unroll
      for (int r = 0; r < 4; r++){
        float mx = lm[r];
#pragma unroll
        for (int m = 1; m < 16; m <<= 1) mx = fmaxf(mx, __shfl_xor(mx, m));
        float nm = fmaxf(mrow[r], mx * SC2);
        float alpha = exp2f(mrow[r] - nm);
        mrow[r] = nm;
#pragma unroll
        for (int nt = 0; nt < 4; nt++) oacc[nt][r] *= alpha;
        oacc5[r] *= alpha;
      }
    }
    // P = exp2(S*SC2 - mrow), stored transposed: Pt[wv][k][q], b64 packed stores
#pragma unroll
    for (int nt = 0; nt < 4; nt++){
      bf16x4 w;
#pragma unroll
      for (int r = 0; r < 4; r++) w[r] = (bf16)exp2f(fmaf(sacc[nt][r], SC2, -mrow[r]));
      *(bf16x4*)&Pt[wv][nt*16 + l15][quad*4] = w;
    }
    // A-frag via HW transpose read: pf[s][j] = Pt[wv][s*32+quad*8+j][l15]
    bf16x8 pf[2];
    {
      bf16x4 t00, t01, t10, t11;
      const bf16* pr0 = &Pt[wv][     quad*8][l15];
      const bf16* pr1 = &Pt[wv][32 + quad*8][l15];
      asm volatile("ds_read_b64_tr_b16 %0, %1"            : "=v"(t00) : "v"(AS3(pr0)) : "memory");
      asm volatile("ds_read_b64_tr_b16 %0, %1 offset:128" : "=v"(t01) : "v"(AS3(pr0)) : "memory");
      asm volatile("ds_read_b64_tr_b16 %0, %1"            : "=v"(t10) : "v"(AS3(pr1)) : "memory");
      asm volatile("ds_read_b64_tr_b16 %0, %1 offset:128" : "=v"(t11) : "v"(AS3(pr1)) : "memory");
      asm volatile("s_waitcnt lgkmcnt(0)" ::: "memory");   // rule #18 fence
      __builtin_amdgcn_sched_barrier(0);
#pragma unroll
      for (int j = 0; j < 4; j++){
        pf[0][j] = t00[j]; pf[0][j+4] = t01[j];
        pf[1][j] = t10[j]; pf[1][j+4] = t11[j];
      }
    }
    // PV with swizzled Vt reads + ones-column row-sum
    __builtin_amdgcn_s_setprio(1);
#pragma unroll
    for (int nt = 0; nt < 4; nt++){
      int d = nt*16 + l15;
      int sw = (d & 7) ^ ((d >> 3) & 7);
#pragma unroll
      for (int s = 0; s < 2; s++){
        bf16x8 vf = *(const bf16x8*)&Vt[d*64 + (((s*4 + quad) ^ sw) << 3)];
        oacc[nt] = __builtin_amdgcn_mfma_f32_16x16x32_bf16(pf[s], vf, oacc[nt], 0, 0, 0);
      }
    }
    oacc5 = __builtin_amdgcn_mfma_f32_16x16x32_bf16(pf[0], onesf, oacc5, 0, 0, 0);
    oacc5 = __builtin_amdgcn_mfma_f32_16x16x32_bf16(pf[1], onesf, oacc5, 0, 0, 0);
    __builtin_amdgcn_s_setprio(0);
  }
  // epilogue: l lives in lane (quad*16 + 0) of each quad-group, col 0
#pragma unroll
  for (int r = 0; r < 4; r++){
    float l = __shfl(oacc5[r], lane & 48);
    float inv = __builtin_amdgcn_rcpf(l);
    int row = q0 + wv*16 + quad*4 + r;
#pragma unroll
    for (int nt = 0; nt < 4; nt++)
      o[((size_t)b*Kc + row)*Dc + hh*64 + nt*16 + l15] = (bf16)(oacc[nt][r] * inv);
  }
}

// ---------------------------------------------------------------- scatter-add to fp32 output
__global__ __launch_bounds__(256) void scatter_kernel(const float* __restrict__ x,
    const float* __restrict__ h, const float* __restrict__ gate,
    const int* __restrict__ slot, float* __restrict__ out){
  int row = blockIdx.x;                       // b*Tc + t, grid 8192
  int b = row >> 12;
  int d = threadIdx.x * 4;
  const float* xr = x + (size_t)row * Dc;
  float* orow = out + (size_t)row * Dc;
  int sl = slot[row];
  if (sl >= 0 && sl < Kc){
    float g = gate[b*Kc + sl];
    const float* hr = h + ((size_t)b*Kc + sl) * Dc;
    float4 xv = *(const float4*)(xr + d);
    float4 hv = *(const float4*)(hr + d);
    float4 ov = { xv.x + g*hv.x, xv.y + g*hv.y, xv.z + g*hv.z, xv.w + g*hv.w };
    *(float4*)(orow + d) = ov;
  } else {
    *(float4*)(orow + d) = *(const float4*)(xr + d);
  }
}

// ---------------------------------------------------------------- launch
extern "C" void kernel_launch(void* const* d_in, const int* in_sizes, int n_in,
                              void* d_out, int out_size, void* d_ws, size_t ws_size,
                              hipStream_t stream)
{
  const float* x        = (const float*)d_in[0];
  const float* router_w = (const float*)d_in[1];
  const float* router_b = (const float*)d_in[2];
  const float* ln1_w    = (const float*)d_in[3];
  const float* ln1_b    = (const float*)d_in[4];
  const float* wqkv     = (const float*)d_in[5];
  const float* wo       = (const float*)d_in[6];
  const float* ln2_w    = (const float*)d_in[7];
  const float* ln2_b    = (const float*)d_in[8];
  const float* w1       = (const float*)d_in[9];
  const float* w2       = (const float*)d_in[10];
  float* out = (float*)d_out;

  // workspace layout (bytes), 4 KB pad between regions
  char* ws = (char*)d_ws;
  if (ws_size < 84029440u) return;
  float* logits = (float*)(ws + 0);            //  32768
  int*   slot   = (int*)  (ws + 36864);        //  32768
  int*   sel    = (int*)  (ws + 73728);        //  16384
  float* gate   = (float*)(ws + 94208);        //  16384
  float* h      = (float*)(ws + 114688);       //  16 MB fp32 residual stream [4096,1024]
  bf16*  y      = (bf16*) (ws + 16896000);     //  8 MB  (aliases attention output o)
  bf16*  big    = (bf16*) (ws + 25288704);     //  32 MB (qkv [4096,3072] / gelu [4096,4096])
  bf16*  wqkvT  = (bf16*) (ws + 58847232);     //  6 MB
  bf16*  woT    = (bf16*) (ws + 65142784);     //  2 MB
  bf16*  w1T    = (bf16*) (ws + 67244032);     //  8 MB
  bf16*  w2T    = (bf16*) (ws + 75636736);     //  8 MB; end = 84025344

  router_kernel<<<2048, 256, 0, stream>>>(x, router_w, router_b, logits, slot, sel, gate);
  topk_kernel<<<256, 256, 0, stream>>>(logits, slot, sel, gate);
  gather_kernel<<<4096, 256, 0, stream>>>(x, sel, h);

  for (int l = 0; l < 2; l++){
    transpose4_kernel<<<3072, 256, 0, stream>>>(
        wqkv + (size_t)l*Dc*3*Dc, wo + (size_t)l*Dc*Dc,
        w1 + (size_t)l*Dc*Fc,     w2 + (size_t)l*Fc*Dc,
        wqkvT, woT, w1T, w2T);

    ln_kernel<<<4096, 256, 0, stream>>>(h, ln1_w + l*Dc, ln1_b + l*Dc, y);
    gemm_bt_kernel<<<dim3(24,32), 256, 0, stream>>>(y, wqkvT, big, nullptr, 4096, 3*Dc, Dc, 0);
    flash_kernel<<<1024, 256, 0, stream>>>(big, y);                       // y now holds attn output o
    gemm_bt64_kernel<<<dim3(16,32), 256, 0, stream>>>(y, woT, nullptr, h, 4096, Dc, Dc, 1);
    ln_kernel<<<4096, 256, 0, stream>>>(h, ln2_w + l*Dc, ln2_b + l*Dc, y);
    gemm_bt_kernel<<<dim3(32,32), 256, 0, stream>>>(y, w1T, big, nullptr, 4096, Fc, Dc, 2);
    gemm_bt64_kernel<<<dim3(16,32), 256, 0, stream>>>(big, w2T, nullptr, h, 4096, Dc, Fc, 1);
  }

  scatter_kernel<<<8192, 256, 0, stream>>>(x, h, gate, slot, out);
}

// Round 7
// 792.990 us; speedup vs baseline: 1.2886x; 1.0360x over previous
//
#include <hip/hip_runtime.h>
#include <cmath>

typedef __bf16 bf16;
typedef __bf16 bf16x2 __attribute__((ext_vector_type(2)));
typedef __bf16 bf16x4 __attribute__((ext_vector_type(4)));
typedef __bf16 bf16x8 __attribute__((ext_vector_type(8)));
typedef float  f32x4  __attribute__((ext_vector_type(4)));

#define AS1(p) ((const __attribute__((address_space(1))) void*)(p))
#define AS3(p) ((__attribute__((address_space(3))) void*)(p))

// problem constants
constexpr int Bc = 2, Tc = 4096, Dc = 1024, Hc = 16, Fc = 4096, Kc = 2048;

// ---------------------------------------------------------------- router (fp32) + init fused
__global__ __launch_bounds__(256) void router_kernel(const float* __restrict__ x,
    const float* __restrict__ rw, const float* __restrict__ rb, float* __restrict__ logits,
    int* __restrict__ slot, int* __restrict__ sel, float* __restrict__ gate){
  int flat = blockIdx.x * 256 + threadIdx.x;       // grid 2048 -> 524288
  if (flat < Bc * Tc) slot[flat] = -1;             // defensive init (no poison survives)
  if (flat < Bc * Kc){ sel[flat] = flat & (Kc - 1); gate[flat] = 0.f; }
  int wv = threadIdx.x >> 6, lane = threadIdx.x & 63;
  int token = blockIdx.x * 4 + wv;                 // 8192 tokens
  const float* xr = x + (size_t)token * Dc;
  float s = 0.f;
#pragma unroll
  for (int i = 0; i < 16; i++){ int d = lane + i*64; s += xr[d] * rw[d]; }
#pragma unroll
  for (int m = 32; m; m >>= 1) s += __shfl_xor(s, m);
  if (lane == 0) logits[token] = s + rb[0];
}

// ---------------------------------------------------------------- top-k by rank counting (parallelized)
__global__ __launch_bounds__(256) void topk_kernel(const float* __restrict__ logits,
    int* __restrict__ slot, int* __restrict__ sel, float* __restrict__ gate){
  __shared__ float lg[Tc];
  int b = blockIdx.x >> 7, seg = blockIdx.x & 127;  // grid 256
  const float* lb = logits + (size_t)b * Tc;
#pragma unroll
  for (int i = 0; i < 4; i++)
    *(float4*)&lg[(threadIdx.x + i*256)*4] = *(const float4*)&lb[(threadIdx.x + i*256)*4];
  __syncthreads();
  int t = seg * 32 + (threadIdx.x >> 3);            // this 8-lane group's token
  int c = threadIdx.x & 7;                           // chunk id within the scan
  float v = lg[t];
  int rank = 0;
#pragma unroll 4
  for (int j4 = c*128; j4 < c*128 + 128; j4++){
    float4 u4 = *(const float4*)&lg[j4*4];
    int j = j4*4;
    rank += (u4.x > v) || (u4.x == v && (j+0) < t);
    rank += (u4.y > v) || (u4.y == v && (j+1) < t);
    rank += (u4.z > v) || (u4.z == v && (j+2) < t);
    rank += (u4.w > v) || (u4.w == v && (j+3) < t);
  }
  rank += __shfl_xor(rank, 1);                       // 8-lane groups are wave-contiguous
  rank += __shfl_xor(rank, 2);
  rank += __shfl_xor(rank, 4);
  if (c == 0 && rank < Kc){
    sel [b*Kc + rank] = t;
    gate[b*Kc + rank] = 1.f / (1.f + expf(-v));
    slot[b*Tc + t] = rank;
  }
}

// ---------------------------------------------------------------- gather to fp32 h
__global__ __launch_bounds__(256) void gather_kernel(const float* __restrict__ x,
    const int* __restrict__ sel, float* __restrict__ h){
  int row = blockIdx.x;                            // b*Kc + k, grid 4096
  int b = row >> 11;
  int t = sel[row];
  t = (t < 0) ? 0 : (t >= Tc ? Tc - 1 : t);        // clamp: fault -> wrong answer
  const float* xr = x + ((size_t)b * Tc + t) * Dc;
  float* hr = h + (size_t)row * Dc;
  int d = threadIdx.x * 4;
  *(float4*)(hr + d) = *(const float4*)(xr + d);
}

// ---------------------------------------------------------------- layernorm fp32->bf16
__global__ __launch_bounds__(256) void ln_kernel(const float* __restrict__ h,
    const float* __restrict__ w, const float* __restrict__ bb, bf16* __restrict__ y){
  __shared__ float red[4], red2[4];
  int row = blockIdx.x, t = threadIdx.x;
  int wv = t >> 6, lane = t & 63;
  const float* hr = h + (size_t)row * Dc;
  float4 x4 = *(const float4*)(hr + t*4);
  float s = x4.x + x4.y + x4.z + x4.w;
#pragma unroll
  for (int m = 32; m; m >>= 1) s += __shfl_xor(s, m);
  if (lane == 0) red[wv] = s;
  __syncthreads();
  float mu = (red[0]+red[1]+red[2]+red[3]) * (1.f/Dc);
  float d0 = x4.x-mu, d1 = x4.y-mu, d2 = x4.z-mu, d3 = x4.w-mu;
  float q = d0*d0 + d1*d1 + d2*d2 + d3*d3;
#pragma unroll
  for (int m = 32; m; m >>= 1) q += __shfl_xor(q, m);
  if (lane == 0) red2[wv] = q;
  __syncthreads();
  float var = (red2[0]+red2[1]+red2[2]+red2[3]) * (1.f/Dc);
  float rs = rsqrtf(var + 1e-5f);
  bf16* yr = y + (size_t)row * Dc;
  int d = t * 4;
  float xv[4] = {x4.x, x4.y, x4.z, x4.w};
#pragma unroll
  for (int i = 0; i < 4; i++)
    yr[d+i] = (bf16)((xv[i]-mu) * rs * w[d+i] + bb[d+i]);
}

// ---------------------------------------------------------------- weight transpose fp32 -> bf16 (tile body)
__device__ __forceinline__ void transpose_tile(const float* __restrict__ in,
    bf16* __restrict__ out, int R, int C, int bx, int by, bf16 (*tile)[72]){
  int c0 = bx * 64, r0 = by * 64;
  int t = threadIdx.x;
#pragma unroll
  for (int i = 0; i < 2; i++){
    int ch = t + i*256;
    int row = ch >> 3, col8 = (ch & 7) * 8;
    const float* src = in + (size_t)(r0+row)*C + c0 + col8;
    float4 a = *(const float4*)src;
    float4 b = *(const float4*)(src + 4);
    bf16x8 v;
    v[0]=(bf16)a.x; v[1]=(bf16)a.y; v[2]=(bf16)a.z; v[3]=(bf16)a.w;
    v[4]=(bf16)b.x; v[5]=(bf16)b.y; v[6]=(bf16)b.z; v[7]=(bf16)b.w;
    *(bf16x8*)&tile[row][col8] = v;
  }
  __syncthreads();
#pragma unroll
  for (int i = 0; i < 2; i++){
    int ch = t + i*256;
    int orow = ch >> 3, oc8 = (ch & 7) * 8;
    bf16x8 v;
#pragma unroll
    for (int j = 0; j < 8; j++) v[j] = tile[oc8+j][orow];
    *(bf16x8*)(out + (size_t)(c0+orow)*R + r0 + oc8) = v;
  }
}

// all 4 per-layer weight transposes in one launch (grid 3072)
__global__ __launch_bounds__(256) void transpose4_kernel(
    const float* __restrict__ wqkv, const float* __restrict__ wo,
    const float* __restrict__ w1,   const float* __restrict__ w2,
    bf16* __restrict__ wqkvT, bf16* __restrict__ woT,
    bf16* __restrict__ w1T,   bf16* __restrict__ w2T){
  __shared__ __attribute__((aligned(16))) bf16 tile[64][72];
  int id = blockIdx.x;
  if (id < 768)        transpose_tile(wqkv, wqkvT, Dc, 3*Dc, id % 48,        id / 48,        tile);
  else if (id < 1024){ int t = id - 768;  transpose_tile(wo, woT, Dc, Dc,   t % 16,         t / 16,         tile); }
  else if (id < 2048){ int t = id - 1024; transpose_tile(w1, w1T, Dc, Fc,   t % 64,         t / 64,         tile); }
  else               { int t = id - 2048; transpose_tile(w2, w2T, Fc, Dc,   t % 16,         t / 16,         tile); }
}

// fast gelu (tanh approx == sigmoid form), exp2-based
__device__ __forceinline__ float fast_gelu(float v){
  float u = exp2f(v * (1.f + 0.044715f*v*v) * -2.30220772f);  // 2*0.79788456*log2(e)
  return v * __builtin_amdgcn_rcpf(1.f + u);
}

// ---------------------------------------------------------------- MFMA GEMM 128x128, BK=64 (unchanged, R2-proven)
__global__ __launch_bounds__(256) void gemm_bt_kernel(
    const bf16* __restrict__ A, const bf16* __restrict__ Bt,
    bf16* __restrict__ Cbf, float* __restrict__ Cf,
    int M, int N, int Kd, int mode)
{
  __shared__ __attribute__((aligned(16))) bf16 As[128*64];
  __shared__ __attribute__((aligned(16))) bf16 Bs[128*64];
  const int tid = threadIdx.x;
  const int wv = tid >> 6, lane = tid & 63;
  const int wm = wv & 1, wn = wv >> 1;
  const int quad = lane >> 4, l15 = lane & 15;
  const int m0 = blockIdx.y * 128, n0 = blockIdx.x * 128;
  f32x4 acc[4][4] = {};

  const int arow = tid >> 3;
  const int acol = ((tid & 7) ^ (arow & 7)) * 8;
  const bf16* Ag = A  + (size_t)(m0 + arow) * Kd + acol;
  const bf16* Bg = Bt + (size_t)(n0 + arow) * Kd + acol;
  char* AsB = (char*)As;
  char* BsB = (char*)Bs;
  const size_t rstep = (size_t)32 * Kd;

  const bf16* Ab = As + (size_t)(wm*64 + l15) * 64;
  const bf16* Bb = Bs + (size_t)(wn*64 + l15) * 64;
  const int rx = l15 & 7;

  for (int k0 = 0; k0 < Kd; k0 += 64){
    __syncthreads();
#pragma unroll
    for (int i = 0; i < 4; i++){
      __builtin_amdgcn_global_load_lds(AS1(Ag + i*rstep + k0), AS3(AsB + i*4096 + wv*1024), 16, 0, 0);
      __builtin_amdgcn_global_load_lds(AS1(Bg + i*rstep + k0), AS3(BsB + i*4096 + wv*1024), 16, 0, 0);
    }
    __syncthreads();
#pragma unroll
    for (int s = 0; s < 2; s++){
      const int ax = ((s*4 + quad) ^ rx) * 8;
      bf16x8 af[4], bfr[4];
#pragma unroll
      for (int mt = 0; mt < 4; mt++) af[mt]  = *(const bf16x8*)(Ab + mt*1024 + ax);
#pragma unroll
      for (int nt = 0; nt < 4; nt++) bfr[nt] = *(const bf16x8*)(Bb + nt*1024 + ax);
#pragma unroll
      for (int mt = 0; mt < 4; mt++)
#pragma unroll
        for (int nt = 0; nt < 4; nt++)
          acc[mt][nt] = __builtin_amdgcn_mfma_f32_16x16x32_bf16(af[mt], bfr[nt], acc[mt][nt], 0, 0, 0);
    }
  }
#pragma unroll
  for (int mt = 0; mt < 4; mt++){
    int rr0 = m0 + wm*64 + mt*16 + (lane>>4)*4;
#pragma unroll
    for (int nt = 0; nt < 4; nt++){
      int cc = n0 + wn*64 + nt*16 + (lane&15);
#pragma unroll
      for (int r = 0; r < 4; r++){
        float v = acc[mt][nt][r];
        size_t idx = (size_t)(rr0 + r) * N + cc;
        if (mode == 0)      Cbf[idx] = (bf16)v;
        else if (mode == 1) Cf[idx] += v;
        else                Cbf[idx] = (bf16)fast_gelu(v);
      }
    }
  }
}

// ---------------------------------------------------------------- MFMA GEMM 128x64, BK=64
// mode 0: Cbf = bf16(acc); mode 1: Cf += acc; mode 2: Cbf = bf16(gelu(acc));
// mode 3 (final-layer w2 GEMM): fused residual+gate+scatter -- reads Cf (h, read-only),
// writes out[b,t,:] = x[b,t,:] + gate*(h + acc) for t = sel[row]. scatter_kernel then
// only handles unselected rows (slot<0) -> disjoint, each out element written once.
__global__ __launch_bounds__(256) void gemm_bt64_kernel(
    const bf16* __restrict__ A, const bf16* __restrict__ Bt,
    bf16* __restrict__ Cbf, float* __restrict__ Cf,
    int M, int N, int Kd, int mode,
    const float* __restrict__ xg, const int* __restrict__ sel,
    const float* __restrict__ gatep, float* __restrict__ outp)
{
  __shared__ __attribute__((aligned(16))) bf16 As[128*64];
  __shared__ __attribute__((aligned(16))) bf16 Bs[64*64];
  const int tid = threadIdx.x;
  const int wv = tid >> 6, lane = tid & 63;
  const int wm = wv >> 1, wn = wv & 1;            // 2x2 waves: wave = 64(m) x 32(n)
  const int quad = lane >> 4, l15 = lane & 15;
  const int m0 = blockIdx.y * 128, n0 = blockIdx.x * 64;
  f32x4 acc[4][2] = {};

  const int arow = tid >> 3;
  const int acol = ((tid & 7) ^ (arow & 7)) * 8;
  const bf16* Ag = A  + (size_t)(m0 + arow) * Kd + acol;
  const bf16* Bg = Bt + (size_t)(n0 + arow) * Kd + acol;
  char* AsB = (char*)As;
  char* BsB = (char*)Bs;
  const size_t rstep = (size_t)32 * Kd;

  const bf16* Ab = As + (size_t)(wm*64 + l15) * 64;
  const bf16* Bb = Bs + (size_t)(wn*32 + l15) * 64;
  const int rx = l15 & 7;

  for (int k0 = 0; k0 < Kd; k0 += 64){
    __syncthreads();
#pragma unroll
    for (int i = 0; i < 4; i++)
      __builtin_amdgcn_global_load_lds(AS1(Ag + i*rstep + k0), AS3(AsB + i*4096 + wv*1024), 16, 0, 0);
#pragma unroll
    for (int i = 0; i < 2; i++)
      __builtin_amdgcn_global_load_lds(AS1(Bg + i*rstep + k0), AS3(BsB + i*4096 + wv*1024), 16, 0, 0);
    __syncthreads();
#pragma unroll
    for (int s = 0; s < 2; s++){
      const int ax = ((s*4 + quad) ^ rx) * 8;
      bf16x8 af[4], bfr[2];
#pragma unroll
      for (int mt = 0; mt < 4; mt++) af[mt]  = *(const bf16x8*)(Ab + mt*1024 + ax);
#pragma unroll
      for (int nt = 0; nt < 2; nt++) bfr[nt] = *(const bf16x8*)(Bb + nt*1024 + ax);
#pragma unroll
      for (int mt = 0; mt < 4; mt++)
#pragma unroll
        for (int nt = 0; nt < 2; nt++)
          acc[mt][nt] = __builtin_amdgcn_mfma_f32_16x16x32_bf16(af[mt], bfr[nt], acc[mt][nt], 0, 0, 0);
    }
  }
  if (mode == 3){
#pragma unroll
    for (int mt = 0; mt < 4; mt++){
      int rr0 = m0 + wm*64 + mt*16 + quad*4;
#pragma unroll
      for (int r = 0; r < 4; r++){
        int row = rr0 + r;                       // b*Kc + k
        int bb = row >> 11;
        int t  = sel[row];
        t = (t < 0) ? 0 : (t >= Tc ? Tc - 1 : t);
        float g = gatep[row];
        const size_t obase = ((size_t)bb * Tc + t) * (size_t)Dc;
#pragma unroll
        for (int nt = 0; nt < 2; nt++){
          int cc = n0 + wn*32 + nt*16 + l15;
          float hv = Cf[(size_t)row * N + cc] + acc[mt][nt][r];
          outp[obase + cc] = xg[obase + cc] + g * hv;
        }
      }
    }
    return;
  }
#pragma unroll
  for (int mt = 0; mt < 4; mt++){
    int rr0 = m0 + wm*64 + mt*16 + (lane>>4)*4;
#pragma unroll
    for (int nt = 0; nt < 2; nt++){
      int cc = n0 + wn*32 + nt*16 + (lane&15);
#pragma unroll
      for (int r = 0; r < 4; r++){
        float v = acc[mt][nt][r];
        size_t idx = (size_t)(rr0 + r) * N + cc;
        if (mode == 0)      Cbf[idx] = (bf16)v;
        else if (mode == 1) Cf[idx] += v;
        else                Cbf[idx] = (bf16)fast_gelu(v);
      }
    }
  }
}

// ---------------------------------------------------------------- flash attention v4 (reverted; R1-R3 proven)
// grid 1024 = 32 qtiles x 16 heads x 2 batch; 256 threads; wave owns 16 q-rows.
// tr_read-V variants (v5/v6) REFUTED this session: identical absmax failure under two
// different sync structures -> V-path model wrong on HW. Keep pack-loop Vt staging.
__global__ __launch_bounds__(256) void flash_kernel(const bf16* __restrict__ qkv, bf16* __restrict__ o){
  __shared__ __attribute__((aligned(16))) bf16 Ks[64][72];
  __shared__ __attribute__((aligned(16))) bf16 Vt[64*64];
  __shared__ __attribute__((aligned(16))) bf16 Pt[4][64][16];  // per-wave P, transposed [kcol][qrow]
  const int tid = threadIdx.x, wv = tid >> 6, lane = tid & 63;
  const int quad = lane >> 4, l15 = lane & 15;
  const int bid = blockIdx.x;
  const int qt = bid & 31, hh = (bid >> 5) & 15, b = bid >> 9;
  const int q0 = qt * 64;
  const size_t base = (size_t)b * Kc * (3*Dc);
  const float SC2 = 0.125f * 1.44269504f;          // 1/sqrt(64) * log2(e)

  const int sp8 = (tid & 7) * 8;                   // d-col group for staging
  const int kr0 = tid >> 3, kr1 = kr0 + 32;        // K staging rows
  const int vr0 = (tid >> 3) * 2;                  // V staging rows (pair vr0, vr0+1)
  const int vg = vr0 >> 3, vlo = vr0 & 7, vsw = sp8 >> 3;

  // Q direct to registers (A-frag)
  bf16x8 qf[2];
  {
    const bf16* qr = qkv + base + (size_t)(q0 + wv*16 + l15)*(3*Dc) + hh*64 + quad*8;
    qf[0] = *(const bf16x8*)(qr);
    qf[1] = *(const bf16x8*)(qr + 32);
  }

  // prefetch K/V tile 0
  const bf16* kp0 = qkv + base + (size_t)kr0*(3*Dc) +   Dc + hh*64 + sp8;
  const bf16* kp1 = qkv + base + (size_t)kr1*(3*Dc) +   Dc + hh*64 + sp8;
  const bf16* vp0 = qkv + base + (size_t)vr0*(3*Dc) + 2*Dc + hh*64 + sp8;
  const bf16* vp1 = vp0 + 3*Dc;
  bf16x8 kpre0 = *(const bf16x8*)kp0;
  bf16x8 kpre1 = *(const bf16x8*)kp1;
  bf16x8 vpre0 = *(const bf16x8*)vp0;
  bf16x8 vpre1 = *(const bf16x8*)vp1;
  const int TSTRIDE = 64 * 3 * Dc;

  // ones B-frag: column 0 of the virtual 5th V tile
  bf16x8 onesf;
#pragma unroll
  for (int j = 0; j < 8; j++) onesf[j] = (bf16)(l15 == 0 ? 1.f : 0.f);

  f32x4 oacc[4] = {};
  f32x4 oacc5 = {};                                 // row-sums of P (alpha-chained)
  float mrow[4];
#pragma unroll
  for (int r = 0; r < 4; r++) mrow[r] = -1e30f;

  for (int kt = 0; kt < 32; kt++){
    __syncthreads();                               // prev tile's readers done
    // stage K (b128) and V (packed kv-pairs, b32)
    *(bf16x8*)&Ks[kr0][sp8] = kpre0;
    *(bf16x8*)&Ks[kr1][sp8] = kpre1;
#pragma unroll
    for (int j = 0; j < 8; j++){
      bf16x2 pr; pr[0] = vpre0[j]; pr[1] = vpre1[j];
      *(bf16x2*)&Vt[(sp8 + j)*64 + ((vg ^ j ^ vsw) << 3) + vlo] = pr;
    }
    __syncthreads();
    // prefetch next tile (overlaps compute below)
    if (kt < 31){
      kp0 += TSTRIDE; kp1 += TSTRIDE; vp0 += TSTRIDE; vp1 += TSTRIDE;
      kpre0 = *(const bf16x8*)kp0;
      kpre1 = *(const bf16x8*)kp1;
      vpre0 = *(const bf16x8*)vp0;
      vpre1 = *(const bf16x8*)vp1;
    }
    // S = Q K^T
    f32x4 sacc[4] = {};
    __builtin_amdgcn_s_setprio(1);
#pragma unroll
    for (int nt = 0; nt < 4; nt++)
#pragma unroll
      for (int s = 0; s < 2; s++){
        bf16x8 kf = *(const bf16x8*)&Ks[nt*16 + l15][s*32 + quad*8];
        sacc[nt] = __builtin_amdgcn_mfma_f32_16x16x32_bf16(qf[s], kf, sacc[nt], 0, 0, 0);
      }
    __builtin_amdgcn_s_setprio(0);
    // ---- online softmax, exp2 domain, deferred rescale (THR = 8) ----
    float lm[4];
#pragma unroll
    for (int r = 0; r < 4; r++)
      lm[r] = fmaxf(fmaxf(sacc[0][r], sacc[1][r]), fmaxf(sacc[2][r], sacc[3][r]));
    bool ok = true;
#pragma unroll
    for (int r = 0; r < 4; r++) ok = ok && (lm[r] * SC2 <= mrow[r] + 8.f);
    if (!__all((int)ok)){
      // slow path: full 16-lane max reduce + alpha rescale (tile 0 + rare growth)
#pragma unroll
      for (int r = 0; r < 4; r++){
        float mx = lm[r];
#pragma unroll
        for (int m = 1; m < 16; m <<= 1) mx = fmaxf(mx, __shfl_xor(mx, m));
        float nm = fmaxf(mrow[r], mx * SC2);
        float alpha = exp2f(mrow[r] - nm);
        mrow[r] = nm;
#pragma unroll
        for (int nt = 0; nt < 4; nt++) oacc[nt][r] *= alpha;
        oacc5[r] *= alpha;
      }
    }
    // P = exp2(S*SC2 - mrow), stored transposed: Pt[wv][k][q], b64 packed stores
#pragma unroll
    for (int nt = 0; nt < 4; nt++){
      bf16x4 w;
#pragma unroll
      for (int r = 0; r < 4; r++) w[r] = (bf16)exp2f(fmaf(sacc[nt][r], SC2, -mrow[r]));
      *(bf16x4*)&Pt[wv][nt*16 + l15][quad*4] = w;
    }
    // P A-frag via HW transpose read: pf[s][j] = Pt[wv][s*32+quad*8+j][l15]
    bf16x8 pf[2];
    {
      bf16x4 t00, t01, t10, t11;
      const bf16* pr0 = &Pt[wv][     quad*8][l15];
      const bf16* pr1 = &Pt[wv][32 + quad*8][l15];
      asm volatile("ds_read_b64_tr_b16 %0, %1"            : "=v"(t00) : "v"(AS3(pr0)) : "memory");
      asm volatile("ds_read_b64_tr_b16 %0, %1 offset:128" : "=v"(t01) : "v"(AS3(pr0)) : "memory");
      asm volatile("ds_read_b64_tr_b16 %0, %1"            : "=v"(t10) : "v"(AS3(pr1)) : "memory");
      asm volatile("ds_read_b64_tr_b16 %0, %1 offset:128" : "=v"(t11) : "v"(AS3(pr1)) : "memory");
      asm volatile("s_waitcnt lgkmcnt(0)" ::: "memory");   // rule #18 fence
      __builtin_amdgcn_sched_barrier(0);
#pragma unroll
      for (int j = 0; j < 4; j++){
        pf[0][j] = t00[j]; pf[0][j+4] = t01[j];
        pf[1][j] = t10[j]; pf[1][j+4] = t11[j];
      }
    }
    // PV with swizzled Vt reads + ones-column row-sum
    __builtin_amdgcn_s_setprio(1);
#pragma unroll
    for (int nt = 0; nt < 4; nt++){
      int d = nt*16 + l15;
      int sw = (d & 7) ^ ((d >> 3) & 7);
#pragma unroll
      for (int s = 0; s < 2; s++){
        bf16x8 vf = *(const bf16x8*)&Vt[d*64 + (((s*4 + quad) ^ sw) << 3)];
        oacc[nt] = __builtin_amdgcn_mfma_f32_16x16x32_bf16(pf[s], vf, oacc[nt], 0, 0, 0);
      }
    }
    oacc5 = __builtin_amdgcn_mfma_f32_16x16x32_bf16(pf[0], onesf, oacc5, 0, 0, 0);
    oacc5 = __builtin_amdgcn_mfma_f32_16x16x32_bf16(pf[1], onesf, oacc5, 0, 0, 0);
    __builtin_amdgcn_s_setprio(0);
  }
  // epilogue: l lives in lane (quad*16 + 0) of each quad-group, col 0
#pragma unroll
  for (int r = 0; r < 4; r++){
    float l = __shfl(oacc5[r], lane & 48);
    float inv = __builtin_amdgcn_rcpf(l);
    int row = q0 + wv*16 + quad*4 + r;
#pragma unroll
    for (int nt = 0; nt < 4; nt++)
      o[((size_t)b*Kc + row)*Dc + hh*64 + nt*16 + l15] = (bf16)(oacc[nt][r] * inv);
  }
}

// ---------------------------------------------------------------- scatter: unselected rows only
// (selected rows are written by the mode-3 GEMM epilogue; disjoint coverage)
__global__ __launch_bounds__(256) void scatter_kernel(const float* __restrict__ x,
    const int* __restrict__ slot, float* __restrict__ out){
  int row = blockIdx.x;                       // b*Tc + t, grid 8192
  int sl = slot[row];
  if (sl >= 0 && sl < Kc) return;             // written by gemm_bt64 mode 3
  int d = threadIdx.x * 4;
  const float* xr = x + (size_t)row * Dc;
  float* orow = out + (size_t)row * Dc;
  *(float4*)(orow + d) = *(const float4*)(xr + d);
}

// ---------------------------------------------------------------- launch
extern "C" void kernel_launch(void* const* d_in, const int* in_sizes, int n_in,
                              void* d_out, int out_size, void* d_ws, size_t ws_size,
                              hipStream_t stream)
{
  const float* x        = (const float*)d_in[0];
  const float* router_w = (const float*)d_in[1];
  const float* router_b = (const float*)d_in[2];
  const float* ln1_w    = (const float*)d_in[3];
  const float* ln1_b    = (const float*)d_in[4];
  const float* wqkv     = (const float*)d_in[5];
  const float* wo       = (const float*)d_in[6];
  const float* ln2_w    = (const float*)d_in[7];
  const float* ln2_b    = (const float*)d_in[8];
  const float* w1       = (const float*)d_in[9];
  const float* w2       = (const float*)d_in[10];
  float* out = (float*)d_out;

  // workspace layout (bytes), 4 KB pad between regions
  char* ws = (char*)d_ws;
  if (ws_size < 84029440u) return;
  float* logits = (float*)(ws + 0);            //  32768
  int*   slot   = (int*)  (ws + 36864);        //  32768
  int*   sel    = (int*)  (ws + 73728);        //  16384
  float* gate   = (float*)(ws + 94208);        //  16384
  float* h      = (float*)(ws + 114688);       //  16 MB fp32 residual stream [4096,1024]
  bf16*  y      = (bf16*) (ws + 16896000);     //  8 MB  (aliases attention output o)
  bf16*  big    = (bf16*) (ws + 25288704);     //  32 MB (qkv [4096,3072] / gelu [4096,4096])
  bf16*  wqkvT  = (bf16*) (ws + 58847232);     //  6 MB
  bf16*  woT    = (bf16*) (ws + 65142784);     //  2 MB
  bf16*  w1T    = (bf16*) (ws + 67244032);     //  8 MB
  bf16*  w2T    = (bf16*) (ws + 75636736);     //  8 MB; end = 84025344

  router_kernel<<<2048, 256, 0, stream>>>(x, router_w, router_b, logits, slot, sel, gate);
  topk_kernel<<<256, 256, 0, stream>>>(logits, slot, sel, gate);
  gather_kernel<<<4096, 256, 0, stream>>>(x, sel, h);

  for (int l = 0; l < 2; l++){
    transpose4_kernel<<<3072, 256, 0, stream>>>(
        wqkv + (size_t)l*Dc*3*Dc, wo + (size_t)l*Dc*Dc,
        w1 + (size_t)l*Dc*Fc,     w2 + (size_t)l*Fc*Dc,
        wqkvT, woT, w1T, w2T);

    ln_kernel<<<4096, 256, 0, stream>>>(h, ln1_w + l*Dc, ln1_b + l*Dc, y);
    gemm_bt_kernel<<<dim3(24,32), 256, 0, stream>>>(y, wqkvT, big, nullptr, 4096, 3*Dc, Dc, 0);
    flash_kernel<<<1024, 256, 0, stream>>>(big, y);                       // y now holds attn output o
    gemm_bt64_kernel<<<dim3(16,32), 256, 0, stream>>>(y, woT, nullptr, h, 4096, Dc, Dc, 1,
                                                      nullptr, nullptr, nullptr, nullptr);
    ln_kernel<<<4096, 256, 0, stream>>>(h, ln2_w + l*Dc, ln2_b + l*Dc, y);
    gemm_bt_kernel<<<dim3(32,32), 256, 0, stream>>>(y, w1T, big, nullptr, 4096, Fc, Dc, 2);
    if (l == 0)
      gemm_bt64_kernel<<<dim3(16,32), 256, 0, stream>>>(big, w2T, nullptr, h, 4096, Dc, Fc, 1,
                                                        nullptr, nullptr, nullptr, nullptr);
    else
      gemm_bt64_kernel<<<dim3(16,32), 256, 0, stream>>>(big, w2T, nullptr, h, 4096, Dc, Fc, 3,
                                                        x, sel, gate, out);
  }

  scatter_kernel<<<8192, 256, 0, stream>>>(x, slot, out);
}